// Round 1
// baseline (3976.509 us; speedup 1.0000x reference)
//
#include <hip/hip_runtime.h>
#include <math.h>

#define D_MODEL 512
#define NHEADS  8
#define DHEAD   64

// ---------------------------------------------------------------------------
// emb = t @ W + b for the three AdaLN linears. Output layout: [norm][B][2D]
// ---------------------------------------------------------------------------
__global__ __launch_bounds__(256) void adaln_params_kernel(
        const float* __restrict__ t,
        const float* __restrict__ w1, const float* __restrict__ b1,
        const float* __restrict__ w2, const float* __restrict__ b2,
        const float* __restrict__ w4, const float* __restrict__ b4,
        float* __restrict__ emb, int B) {
    int g = blockIdx.x * blockDim.x + threadIdx.x;
    int per = B * 2 * D_MODEL;
    if (g >= 3 * per) return;
    int norm = g / per;
    int rem  = g - norm * per;
    int b = rem / (2 * D_MODEL);
    int c = rem % (2 * D_MODEL);
    const float* W  = (norm == 0) ? w1 : (norm == 1 ? w2 : w4);
    const float* bb = (norm == 0) ? b1 : (norm == 1 ? b2 : b4);
    const float* trow = t + (size_t)b * D_MODEL;
    float acc = bb[c];
    for (int k = 0; k < D_MODEL; ++k)
        acc = fmaf(trow[k], W[(size_t)k * (2 * D_MODEL) + c], acc);
    emb[g] = acc;
}

// ---------------------------------------------------------------------------
// AdaLN apply: h = (x - mu)/sqrt(var+eps) * (1+scale) + shift.  Block per row.
// emb_n layout: [B][2D]  (scale = first D, shift = second D)
// ---------------------------------------------------------------------------
__global__ __launch_bounds__(256) void adaln_apply_kernel(
        const float* __restrict__ x, const float* __restrict__ emb_n,
        float* __restrict__ h, int N) {
    int row = blockIdx.x;
    int b = row / N;
    const float* xr = x + (size_t)row * D_MODEL;
    float* hr = h + (size_t)row * D_MODEL;
    int tid = threadIdx.x;
    float v0 = xr[tid];
    float v1 = xr[tid + 256];
    float s = v0 + v1, sq = v0 * v0 + v1 * v1;
#pragma unroll
    for (int off = 32; off; off >>= 1) {
        s  += __shfl_xor(s, off);
        sq += __shfl_xor(sq, off);
    }
    __shared__ float rs[4], rq[4];
    if ((tid & 63) == 0) { rs[tid >> 6] = s; rq[tid >> 6] = sq; }
    __syncthreads();
    float tot  = rs[0] + rs[1] + rs[2] + rs[3];
    float totq = rq[0] + rq[1] + rq[2] + rq[3];
    float mu  = tot * (1.0f / D_MODEL);
    float var = totq * (1.0f / D_MODEL) - mu * mu;
    float inv = rsqrtf(var + 1e-5f);
    const float* er = emb_n + (size_t)b * (2 * D_MODEL);
    float sc0 = er[tid],       sh0 = er[D_MODEL + tid];
    float sc1 = er[tid + 256], sh1 = er[D_MODEL + tid + 256];
    hr[tid]       = (v0 - mu) * inv * (1.0f + sc0) + sh0;
    hr[tid + 256] = (v1 - mu) * inv * (1.0f + sc1) + sh1;
}

// ---------------------------------------------------------------------------
// fp32 tiled GEMM: C[M,Nc] = A[M,K] @ W[K,Nc] (+bias) (+res).
// 64x64 tile, BK=16, 256 threads, 4x4 micro-tile per thread.
// ---------------------------------------------------------------------------
template<bool BIAS, bool RES>
__global__ __launch_bounds__(256) void gemm64_kernel(
        const float* __restrict__ A, const float* __restrict__ W,
        const float* __restrict__ bias, const float* __restrict__ res,
        float* __restrict__ C, int M, int K, int Nc) {
    __shared__ float As[16][68];   // [k][m], padded for b128 alignment
    __shared__ float Bs[16][64];   // [k][n]
    int tid = threadIdx.x;
    int tx = tid & 15, ty = tid >> 4;
    int m0 = blockIdx.y << 6, n0 = blockIdx.x << 6;
    float acc[4][4] = {};

    int ar = tid >> 2,        ac = (tid & 3) << 2;   // A tile: row 0..63, col 0..12
    int br = tid >> 4,        bc = (tid & 15) << 2;  // B tile: row 0..15, col 0..60
    const float* Ap = A + (size_t)(m0 + ar) * K + ac;
    const float* Wp = W + (size_t)br * Nc + n0 + bc;

    for (int k0 = 0; k0 < K; k0 += 16) {
        float4 av = *(const float4*)(Ap + k0);
        float4 bv = *(const float4*)(Wp + (size_t)k0 * Nc);
        As[ac + 0][ar] = av.x;
        As[ac + 1][ar] = av.y;
        As[ac + 2][ar] = av.z;
        As[ac + 3][ar] = av.w;
        *(float4*)&Bs[br][bc] = bv;
        __syncthreads();
#pragma unroll
        for (int k = 0; k < 16; ++k) {
            float4 ra = *(const float4*)&As[k][ty << 2];
            float4 rb = *(const float4*)&Bs[k][tx << 2];
            float a_[4] = {ra.x, ra.y, ra.z, ra.w};
            float b_[4] = {rb.x, rb.y, rb.z, rb.w};
#pragma unroll
            for (int i = 0; i < 4; ++i)
#pragma unroll
                for (int j = 0; j < 4; ++j)
                    acc[i][j] = fmaf(a_[i], b_[j], acc[i][j]);
        }
        __syncthreads();
    }

    int c0 = n0 + (tx << 2);
#pragma unroll
    for (int i = 0; i < 4; ++i) {
        int r = m0 + (ty << 2) + i;
        float4 v = make_float4(acc[i][0], acc[i][1], acc[i][2], acc[i][3]);
        if (BIAS) {
            float4 bb = *(const float4*)(bias + c0);
            v.x += bb.x; v.y += bb.y; v.z += bb.z; v.w += bb.w;
        }
        if (RES) {
            float4 rr = *(const float4*)(res + (size_t)r * Nc + c0);
            v.x += rr.x; v.y += rr.y; v.z += rr.z; v.w += rr.w;
        }
        *(float4*)(C + (size_t)r * Nc + c0) = v;
    }
}

// ---------------------------------------------------------------------------
// Fused GEGLU FF1: gg[M,2048] = (A@W1+b1)[:, :2048] * gelu((A@W1+b1)[:, 2048:])
// ---------------------------------------------------------------------------
__global__ __launch_bounds__(256) void gemm_geglu_kernel(
        const float* __restrict__ A, const float* __restrict__ W1,
        const float* __restrict__ b1, float* __restrict__ gg, int M, int K) {
    const int NOUT = 4 * D_MODEL;   // 2048
    const int WROW = 8 * D_MODEL;   // 4096
    __shared__ float As[16][68];
    __shared__ float Bu[16][64];
    __shared__ float Bg[16][64];
    int tid = threadIdx.x;
    int tx = tid & 15, ty = tid >> 4;
    int m0 = blockIdx.y << 6, n0 = blockIdx.x << 6;
    float accu[4][4] = {};
    float accg[4][4] = {};

    int ar = tid >> 2, ac = (tid & 3) << 2;
    int br = tid >> 4, bc = (tid & 15) << 2;
    const float* Ap  = A  + (size_t)(m0 + ar) * K + ac;
    const float* Wup = W1 + (size_t)br * WROW + n0 + bc;
    const float* Wgp = Wup + NOUT;

    for (int k0 = 0; k0 < K; k0 += 16) {
        float4 av = *(const float4*)(Ap + k0);
        float4 uv = *(const float4*)(Wup + (size_t)k0 * WROW);
        float4 gv = *(const float4*)(Wgp + (size_t)k0 * WROW);
        As[ac + 0][ar] = av.x;
        As[ac + 1][ar] = av.y;
        As[ac + 2][ar] = av.z;
        As[ac + 3][ar] = av.w;
        *(float4*)&Bu[br][bc] = uv;
        *(float4*)&Bg[br][bc] = gv;
        __syncthreads();
#pragma unroll
        for (int k = 0; k < 16; ++k) {
            float4 ra = *(const float4*)&As[k][ty << 2];
            float4 ru = *(const float4*)&Bu[k][tx << 2];
            float4 rg = *(const float4*)&Bg[k][tx << 2];
            float a_[4] = {ra.x, ra.y, ra.z, ra.w};
            float u_[4] = {ru.x, ru.y, ru.z, ru.w};
            float g_[4] = {rg.x, rg.y, rg.z, rg.w};
#pragma unroll
            for (int i = 0; i < 4; ++i)
#pragma unroll
                for (int j = 0; j < 4; ++j) {
                    accu[i][j] = fmaf(a_[i], u_[j], accu[i][j]);
                    accg[i][j] = fmaf(a_[i], g_[j], accg[i][j]);
                }
        }
        __syncthreads();
    }

    int c0 = n0 + (tx << 2);
#pragma unroll
    for (int i = 0; i < 4; ++i) {
        int r = m0 + (ty << 2) + i;
        float outv[4];
#pragma unroll
        for (int j = 0; j < 4; ++j) {
            int c = c0 + j;
            float u = accu[i][j] + b1[c];
            float g = accg[i][j] + b1[NOUT + c];
            float ge = 0.5f * g * (1.0f + erff(g * 0.70710678118654752f));
            outv[j] = u * ge;
        }
        *(float4*)(gg + (size_t)r * NOUT + c0) = make_float4(outv[0], outv[1], outv[2], outv[3]);
    }
}

// ---------------------------------------------------------------------------
// Flash-style fp32 attention. q,k,v,o layout: [B, Nrows, D_MODEL] with head
// offset h*64. One block = 4 waves = 4 query rows; K/V staged 64x64 in LDS.
// ---------------------------------------------------------------------------
__global__ __launch_bounds__(256) void attn_kernel(
        const float* __restrict__ q, const float* __restrict__ k,
        const float* __restrict__ v, float* __restrict__ o,
        int Nq, int Nk) {
    __shared__ float Ks[64][65];
    __shared__ float Vs[64][65];
    __shared__ float ps[4][64];
    int tid = threadIdx.x;
    int w = tid >> 6, lane = tid & 63;
    int nqb = Nq >> 2;
    int qb = blockIdx.x % nqb;
    int hh = (blockIdx.x / nqb) % NHEADS;
    int b  = blockIdx.x / (nqb * NHEADS);
    int row = (qb << 2) + w;
    size_t qoff = ((size_t)(b * Nq + row)) * D_MODEL + hh * DHEAD;

    float qr[64];
#pragma unroll
    for (int i = 0; i < 16; ++i) {
        float4 tq = *(const float4*)(q + qoff + i * 4);
        qr[4 * i + 0] = tq.x * 0.125f;
        qr[4 * i + 1] = tq.y * 0.125f;
        qr[4 * i + 2] = tq.z * 0.125f;
        qr[4 * i + 3] = tq.w * 0.125f;
    }

    float m = -1e30f, l = 0.0f, oacc = 0.0f;
    size_t kvbase = (size_t)b * Nk * D_MODEL + (size_t)hh * DHEAD;

    for (int kb = 0; kb < Nk; kb += 64) {
        __syncthreads();   // all waves done with previous Ks/Vs
#pragma unroll
        for (int e = tid; e < 4096; e += 256) {
            int r = e >> 6, c = e & 63;
            size_t off = kvbase + (size_t)(kb + r) * D_MODEL + c;
            Ks[r][c] = k[off];
            Vs[r][c] = v[off];
        }
        __syncthreads();

        // score for key (kb + lane)
        float s = 0.0f;
#pragma unroll
        for (int d = 0; d < 64; ++d) s = fmaf(qr[d], Ks[lane][d], s);

        float mb = s;
#pragma unroll
        for (int off = 32; off; off >>= 1) mb = fmaxf(mb, __shfl_xor(mb, off));
        float mn = fmaxf(m, mb);
        float p = __expf(s - mn);
        float alpha = __expf(m - mn);
        float psum = p;
#pragma unroll
        for (int off = 32; off; off >>= 1) psum += __shfl_xor(psum, off);
        l = l * alpha + psum;
        ps[w][lane] = p;
        __syncthreads();

        // PV: this lane owns output dim d = lane
        float acc = 0.0f;
#pragma unroll
        for (int jj = 0; jj < 64; ++jj)
            acc = fmaf(ps[w][jj], Vs[jj][lane], acc);
        oacc = oacc * alpha + acc;
        m = mn;
    }
    o[qoff + lane] = oacc / l;
}

// ---------------------------------------------------------------------------
extern "C" void kernel_launch(void* const* d_in, const int* in_sizes, int n_in,
                              void* d_out, int out_size, void* d_ws, size_t ws_size,
                              hipStream_t stream) {
    const float* x    = (const float*)d_in[0];
    const float* t    = (const float*)d_in[1];
    const float* cond = (const float*)d_in[2];
    const float* n1_w = (const float*)d_in[3];
    const float* n1_b = (const float*)d_in[4];
    const float* n2_w = (const float*)d_in[5];
    const float* n2_b = (const float*)d_in[6];
    const float* n4_w = (const float*)d_in[7];
    const float* n4_b = (const float*)d_in[8];
    const float* a1_q = (const float*)d_in[9];
    const float* a1_k = (const float*)d_in[10];
    const float* a1_v = (const float*)d_in[11];
    const float* a1_o = (const float*)d_in[12];
    const float* a1_ob= (const float*)d_in[13];
    const float* a2_q = (const float*)d_in[14];
    const float* a2_k = (const float*)d_in[15];
    const float* a2_v = (const float*)d_in[16];
    const float* a2_o = (const float*)d_in[17];
    const float* a2_ob= (const float*)d_in[18];
    const float* ff_w1= (const float*)d_in[19];
    const float* ff_b1= (const float*)d_in[20];
    const float* ff_w2= (const float*)d_in[21];
    const float* ff_b2= (const float*)d_in[22];
    float* out = (float*)d_out;

    const int B  = in_sizes[1] / D_MODEL;              // 2
    const int N  = in_sizes[0] / (B * D_MODEL);        // 2048
    const int Nc = in_sizes[2] / (B * D_MODEL);        // 1024
    const int R  = B * N;                              // 4096
    const int Rc = B * Nc;                             // 2048

    float* wsf = (float*)d_ws;
    float* emb = wsf;                                        // 3*B*1024
    float* h   = emb + (size_t)3 * B * 2 * D_MODEL;          // R*512
    float* qb  = h  + (size_t)R * D_MODEL;                   // R*512
    float* kb  = qb + (size_t)R * D_MODEL;                   // R*512
    float* vb  = kb + (size_t)R * D_MODEL;                   // R*512
    float* gg  = qb;   // GEGLU intermediate [R,2048]: spans qb..vb + one more R*512

    dim3 blk(256);

    adaln_params_kernel<<<dim3((3 * B * 2 * D_MODEL + 255) / 256), blk, 0, stream>>>(
        t, n1_w, n1_b, n2_w, n2_b, n4_w, n4_b, emb, B);

    // ---- block 1: self-attention ------------------------------------------
    adaln_apply_kernel<<<dim3(R), blk, 0, stream>>>(x, emb, h, N);
    gemm64_kernel<false, false><<<dim3(D_MODEL / 64, R / 64), blk, 0, stream>>>(
        h, a1_q, nullptr, nullptr, qb, R, D_MODEL, D_MODEL);
    gemm64_kernel<false, false><<<dim3(D_MODEL / 64, R / 64), blk, 0, stream>>>(
        h, a1_k, nullptr, nullptr, kb, R, D_MODEL, D_MODEL);
    gemm64_kernel<false, false><<<dim3(D_MODEL / 64, R / 64), blk, 0, stream>>>(
        h, a1_v, nullptr, nullptr, vb, R, D_MODEL, D_MODEL);
    attn_kernel<<<dim3(B * NHEADS * (N / 4)), blk, 0, stream>>>(qb, kb, vb, h, N, N);
    gemm64_kernel<true, true><<<dim3(D_MODEL / 64, R / 64), blk, 0, stream>>>(
        h, a1_o, a1_ob, x, out, R, D_MODEL, D_MODEL);

    // ---- block 2: cross-attention -----------------------------------------
    adaln_apply_kernel<<<dim3(R), blk, 0, stream>>>(out, emb + (size_t)B * 2 * D_MODEL, h, N);
    gemm64_kernel<false, false><<<dim3(D_MODEL / 64, R / 64), blk, 0, stream>>>(
        h, a2_q, nullptr, nullptr, qb, R, D_MODEL, D_MODEL);
    gemm64_kernel<false, false><<<dim3(D_MODEL / 64, Rc / 64), blk, 0, stream>>>(
        cond, a2_k, nullptr, nullptr, kb, Rc, D_MODEL, D_MODEL);
    gemm64_kernel<false, false><<<dim3(D_MODEL / 64, Rc / 64), blk, 0, stream>>>(
        cond, a2_v, nullptr, nullptr, vb, Rc, D_MODEL, D_MODEL);
    attn_kernel<<<dim3(B * NHEADS * (N / 4)), blk, 0, stream>>>(qb, kb, vb, h, N, Nc);
    gemm64_kernel<true, true><<<dim3(D_MODEL / 64, R / 64), blk, 0, stream>>>(
        h, a2_o, a2_ob, out, out, R, D_MODEL, D_MODEL);

    // ---- GEGLU feed-forward -------------------------------------------------
    adaln_apply_kernel<<<dim3(R), blk, 0, stream>>>(out, emb + (size_t)2 * B * 2 * D_MODEL, h, N);
    gemm_geglu_kernel<<<dim3((4 * D_MODEL) / 64, R / 64), blk, 0, stream>>>(
        h, ff_w1, ff_b1, gg, R, D_MODEL);
    gemm64_kernel<true, true><<<dim3(D_MODEL / 64, R / 64), blk, 0, stream>>>(
        gg, ff_w2, ff_b2, out, out, R, 4 * D_MODEL, D_MODEL);
}

// Round 2
// 790.329 us; speedup vs baseline: 5.0315x; 5.0315x over previous
//
#include <hip/hip_runtime.h>
#include <math.h>

#define D_MODEL 512
#define NHEADS  8
#define DHEAD   64

typedef __bf16  bf16x8 __attribute__((ext_vector_type(8)));
typedef float   f32x4  __attribute__((ext_vector_type(4)));

// ---------------------------------------------------------------------------
// emb = t @ W + b for the three AdaLN linears. Output layout: [norm][B][2D]
// ---------------------------------------------------------------------------
__global__ __launch_bounds__(256) void adaln_params_kernel(
        const float* __restrict__ t,
        const float* __restrict__ w1, const float* __restrict__ b1,
        const float* __restrict__ w2, const float* __restrict__ b2,
        const float* __restrict__ w4, const float* __restrict__ b4,
        float* __restrict__ emb, int B) {
    int g = blockIdx.x * blockDim.x + threadIdx.x;
    int per = B * 2 * D_MODEL;
    if (g >= 3 * per) return;
    int norm = g / per;
    int rem  = g - norm * per;
    int b = rem / (2 * D_MODEL);
    int c = rem % (2 * D_MODEL);
    const float* W  = (norm == 0) ? w1 : (norm == 1 ? w2 : w4);
    const float* bb = (norm == 0) ? b1 : (norm == 1 ? b2 : b4);
    const float* trow = t + (size_t)b * D_MODEL;
    float acc = bb[c];
    for (int k = 0; k < D_MODEL; ++k)
        acc = fmaf(trow[k], W[(size_t)k * (2 * D_MODEL) + c], acc);
    emb[g] = acc;
}

// ---------------------------------------------------------------------------
// AdaLN apply: h = (x - mu)/sqrt(var+eps) * (1+scale) + shift.  Block per row.
// ---------------------------------------------------------------------------
__global__ __launch_bounds__(256) void adaln_apply_kernel(
        const float* __restrict__ x, const float* __restrict__ emb_n,
        float* __restrict__ h, int N) {
    int row = blockIdx.x;
    int b = row / N;
    const float* xr = x + (size_t)row * D_MODEL;
    float* hr = h + (size_t)row * D_MODEL;
    int tid = threadIdx.x;
    float v0 = xr[tid];
    float v1 = xr[tid + 256];
    float s = v0 + v1, sq = v0 * v0 + v1 * v1;
#pragma unroll
    for (int off = 32; off; off >>= 1) {
        s  += __shfl_xor(s, off);
        sq += __shfl_xor(sq, off);
    }
    __shared__ float rs[4], rq[4];
    if ((tid & 63) == 0) { rs[tid >> 6] = s; rq[tid >> 6] = sq; }
    __syncthreads();
    float tot  = rs[0] + rs[1] + rs[2] + rs[3];
    float totq = rq[0] + rq[1] + rq[2] + rq[3];
    float mu  = tot * (1.0f / D_MODEL);
    float var = totq * (1.0f / D_MODEL) - mu * mu;
    float inv = rsqrtf(var + 1e-5f);
    const float* er = emb_n + (size_t)b * (2 * D_MODEL);
    float sc0 = er[tid],       sh0 = er[D_MODEL + tid];
    float sc1 = er[tid + 256], sh1 = er[D_MODEL + tid + 256];
    hr[tid]       = (v0 - mu) * inv * (1.0f + sc0) + sh0;
    hr[tid + 256] = (v1 - mu) * inv * (1.0f + sc1) + sh1;
}

// ---------------------------------------------------------------------------
// fp32 tiled GEMM: C[M,Nc] = A[M,K] @ W[K,Nc] (+bias) (+res).
// ---------------------------------------------------------------------------
template<bool BIAS, bool RES>
__global__ __launch_bounds__(256) void gemm64_kernel(
        const float* __restrict__ A, const float* __restrict__ W,
        const float* __restrict__ bias, const float* __restrict__ res,
        float* __restrict__ C, int M, int K, int Nc) {
    __shared__ float As[16][68];
    __shared__ float Bs[16][64];
    int tid = threadIdx.x;
    int tx = tid & 15, ty = tid >> 4;
    int m0 = blockIdx.y << 6, n0 = blockIdx.x << 6;
    float acc[4][4] = {};

    int ar = tid >> 2,        ac = (tid & 3) << 2;
    int br = tid >> 4,        bc = (tid & 15) << 2;
    const float* Ap = A + (size_t)(m0 + ar) * K + ac;
    const float* Wp = W + (size_t)br * Nc + n0 + bc;

    for (int k0 = 0; k0 < K; k0 += 16) {
        float4 av = *(const float4*)(Ap + k0);
        float4 bv = *(const float4*)(Wp + (size_t)k0 * Nc);
        As[ac + 0][ar] = av.x;
        As[ac + 1][ar] = av.y;
        As[ac + 2][ar] = av.z;
        As[ac + 3][ar] = av.w;
        *(float4*)&Bs[br][bc] = bv;
        __syncthreads();
#pragma unroll
        for (int k = 0; k < 16; ++k) {
            float4 ra = *(const float4*)&As[k][ty << 2];
            float4 rb = *(const float4*)&Bs[k][tx << 2];
            float a_[4] = {ra.x, ra.y, ra.z, ra.w};
            float b_[4] = {rb.x, rb.y, rb.z, rb.w};
#pragma unroll
            for (int i = 0; i < 4; ++i)
#pragma unroll
                for (int j = 0; j < 4; ++j)
                    acc[i][j] = fmaf(a_[i], b_[j], acc[i][j]);
        }
        __syncthreads();
    }

    int c0 = n0 + (tx << 2);
#pragma unroll
    for (int i = 0; i < 4; ++i) {
        int r = m0 + (ty << 2) + i;
        float4 v = make_float4(acc[i][0], acc[i][1], acc[i][2], acc[i][3]);
        if (BIAS) {
            float4 bb = *(const float4*)(bias + c0);
            v.x += bb.x; v.y += bb.y; v.z += bb.z; v.w += bb.w;
        }
        if (RES) {
            float4 rr = *(const float4*)(res + (size_t)r * Nc + c0);
            v.x += rr.x; v.y += rr.y; v.z += rr.z; v.w += rr.w;
        }
        *(float4*)(C + (size_t)r * Nc + c0) = v;
    }
}

// ---------------------------------------------------------------------------
// Fused GEGLU FF1
// ---------------------------------------------------------------------------
__global__ __launch_bounds__(256) void gemm_geglu_kernel(
        const float* __restrict__ A, const float* __restrict__ W1,
        const float* __restrict__ b1, float* __restrict__ gg, int M, int K) {
    const int NOUT = 4 * D_MODEL;
    const int WROW = 8 * D_MODEL;
    __shared__ float As[16][68];
    __shared__ float Bu[16][64];
    __shared__ float Bg[16][64];
    int tid = threadIdx.x;
    int tx = tid & 15, ty = tid >> 4;
    int m0 = blockIdx.y << 6, n0 = blockIdx.x << 6;
    float accu[4][4] = {};
    float accg[4][4] = {};

    int ar = tid >> 2, ac = (tid & 3) << 2;
    int br = tid >> 4, bc = (tid & 15) << 2;
    const float* Ap  = A  + (size_t)(m0 + ar) * K + ac;
    const float* Wup = W1 + (size_t)br * WROW + n0 + bc;
    const float* Wgp = Wup + NOUT;

    for (int k0 = 0; k0 < K; k0 += 16) {
        float4 av = *(const float4*)(Ap + k0);
        float4 uv = *(const float4*)(Wup + (size_t)k0 * WROW);
        float4 gv = *(const float4*)(Wgp + (size_t)k0 * WROW);
        As[ac + 0][ar] = av.x;
        As[ac + 1][ar] = av.y;
        As[ac + 2][ar] = av.z;
        As[ac + 3][ar] = av.w;
        *(float4*)&Bu[br][bc] = uv;
        *(float4*)&Bg[br][bc] = gv;
        __syncthreads();
#pragma unroll
        for (int k = 0; k < 16; ++k) {
            float4 ra = *(const float4*)&As[k][ty << 2];
            float4 ru = *(const float4*)&Bu[k][tx << 2];
            float4 rg = *(const float4*)&Bg[k][tx << 2];
            float a_[4] = {ra.x, ra.y, ra.z, ra.w};
            float u_[4] = {ru.x, ru.y, ru.z, ru.w};
            float g_[4] = {rg.x, rg.y, rg.z, rg.w};
#pragma unroll
            for (int i = 0; i < 4; ++i)
#pragma unroll
                for (int j = 0; j < 4; ++j) {
                    accu[i][j] = fmaf(a_[i], u_[j], accu[i][j]);
                    accg[i][j] = fmaf(a_[i], g_[j], accg[i][j]);
                }
        }
        __syncthreads();
    }

    int c0 = n0 + (tx << 2);
#pragma unroll
    for (int i = 0; i < 4; ++i) {
        int r = m0 + (ty << 2) + i;
        float outv[4];
#pragma unroll
        for (int j = 0; j < 4; ++j) {
            int c = c0 + j;
            float u = accu[i][j] + b1[c];
            float g = accg[i][j] + b1[NOUT + c];
            float ge = 0.5f * g * (1.0f + erff(g * 0.70710678118654752f));
            outv[j] = u * ge;
        }
        *(float4*)(gg + (size_t)r * NOUT + c0) = make_float4(outv[0], outv[1], outv[2], outv[3]);
    }
}

// ---------------------------------------------------------------------------
// bf16 MFMA flash attention.
// Layouts (verified per guide §3): mfma_f32_16x16x32_bf16
//   A-frag: lane holds A[lane&15][(lane>>4)*8 + j], j=0..7 (16B contiguous)
//   B-frag: lane holds B[(lane>>4)*8 + j][lane&15]  (= 16B row of B^T)
//   C/D   : col = lane&15, row = (lane>>4)*4 + reg
// Block: 4 waves x 16 q-rows = 64 q-rows. K-tile = 64 keys.
// K staged [key][d] bf16 (stride 72), V staged transposed Vt[d][key].
// ---------------------------------------------------------------------------
__global__ __launch_bounds__(256) void attn_mfma_kernel(
        const float* __restrict__ q, const float* __restrict__ k,
        const float* __restrict__ v, float* __restrict__ o,
        int Nq, int Nk) {
    __shared__ __attribute__((aligned(16))) __bf16 Ks[64][72];
    __shared__ __attribute__((aligned(16))) __bf16 Vt[64][72];
    __shared__ __attribute__((aligned(16))) __bf16 Pl[4][16][72];

    int tid = threadIdx.x;
    int w = tid >> 6, lane = tid & 63;
    int r = lane & 15, g = lane >> 4;

    int nqb = Nq >> 6;
    int qb = blockIdx.x % nqb;
    int hh = (blockIdx.x / nqb) % NHEADS;
    int b  = blockIdx.x / (nqb * NHEADS);

    // ---- Q fragments (16 rows per wave), pre-scaled by 1/sqrt(d) ----------
    const float* qp = q + ((size_t)(b * Nq + (qb << 6) + (w << 4) + r)) * D_MODEL
                        + hh * DHEAD + (g << 3);
    bf16x8 qf[2];
#pragma unroll
    for (int kh = 0; kh < 2; ++kh) {
        const float* p = qp + kh * 32;
#pragma unroll
        for (int j = 0; j < 8; ++j) qf[kh][j] = (__bf16)(p[j] * 0.125f);
    }

    f32x4 oacc[4];
#pragma unroll
    for (int dt = 0; dt < 4; ++dt) oacc[dt] = (f32x4){0.f, 0.f, 0.f, 0.f};
    float m_r[4] = {-1e30f, -1e30f, -1e30f, -1e30f};
    float l_r[4] = {0.f, 0.f, 0.f, 0.f};

    size_t kvbase = (size_t)b * Nk * D_MODEL + (size_t)hh * DHEAD;

    for (int kb = 0; kb < Nk; kb += 64) {
        if (kb) __syncthreads();
        // ---- stage K [key][d] bf16 ----------------------------------------
        {
            int row = tid >> 2, cb = (tid & 3) << 4;
            const float* src = k + kvbase + (size_t)(kb + row) * D_MODEL + cb;
            bf16x8 a, c;
#pragma unroll
            for (int j = 0; j < 8; ++j) { a[j] = (__bf16)src[j]; c[j] = (__bf16)src[j + 8]; }
            *(bf16x8*)&Ks[row][cb] = a;
            *(bf16x8*)&Ks[row][cb + 8] = c;
        }
        // ---- stage V transposed: Vt[d][key] --------------------------------
        {
            int key = tid >> 2, db = (tid & 3) << 4;
            const float* src = v + kvbase + (size_t)(kb + key) * D_MODEL + db;
#pragma unroll
            for (int i = 0; i < 16; ++i) Vt[db + i][key] = (__bf16)src[i];
        }
        __syncthreads();

        // ---- S = Q K^T : 4 n-tiles x 2 k-halves ----------------------------
        f32x4 sacc[4];
#pragma unroll
        for (int nt = 0; nt < 4; ++nt) sacc[nt] = (f32x4){0.f, 0.f, 0.f, 0.f};
#pragma unroll
        for (int nt = 0; nt < 4; ++nt) {
            bf16x8 k0 = *(const bf16x8*)&Ks[(nt << 4) + r][g << 3];
            bf16x8 k1 = *(const bf16x8*)&Ks[(nt << 4) + r][32 + (g << 3)];
            sacc[nt] = __builtin_amdgcn_mfma_f32_16x16x32_bf16(qf[0], k0, sacc[nt], 0, 0, 0);
            sacc[nt] = __builtin_amdgcn_mfma_f32_16x16x32_bf16(qf[1], k1, sacc[nt], 0, 0, 0);
        }

        // ---- online softmax (rows = (g<<2)+reg, cols across 16-lane group) -
#pragma unroll
        for (int rg = 0; rg < 4; ++rg) {
            float mx = fmaxf(fmaxf(sacc[0][rg], sacc[1][rg]),
                             fmaxf(sacc[2][rg], sacc[3][rg]));
#pragma unroll
            for (int off = 1; off < 16; off <<= 1) mx = fmaxf(mx, __shfl_xor(mx, off));
            float mn = fmaxf(m_r[rg], mx);
            float al = __expf(m_r[rg] - mn);
            m_r[rg] = mn;
            float sum = 0.f;
#pragma unroll
            for (int nt = 0; nt < 4; ++nt) {
                float p = __expf(sacc[nt][rg] - mn);
                sum += p;
                Pl[w][(g << 2) + rg][(nt << 4) + r] = (__bf16)p;
            }
#pragma unroll
            for (int off = 1; off < 16; off <<= 1) sum += __shfl_xor(sum, off);
            l_r[rg] = l_r[rg] * al + sum;
#pragma unroll
            for (int dt = 0; dt < 4; ++dt) {
                oacc[dt][rg] *= al;
            }
        }

        // ---- O += P V : A = P (16x64), B = V (64 x d16-tiles) ---------------
#pragma unroll
        for (int kh = 0; kh < 2; ++kh) {
            bf16x8 pa = *(const bf16x8*)&Pl[w][r][(kh << 5) + (g << 3)];
#pragma unroll
            for (int dt = 0; dt < 4; ++dt) {
                bf16x8 vb = *(const bf16x8*)&Vt[(dt << 4) + r][(kh << 5) + (g << 3)];
                oacc[dt] = __builtin_amdgcn_mfma_f32_16x16x32_bf16(pa, vb, oacc[dt], 0, 0, 0);
            }
        }
    }

    // ---- epilogue: O / l, write fp32 ----------------------------------------
    float* orow = o + ((size_t)(b * Nq + (qb << 6) + (w << 4))) * D_MODEL + hh * DHEAD;
#pragma unroll
    for (int rg = 0; rg < 4; ++rg) {
        float inv = 1.0f / l_r[rg];
#pragma unroll
        for (int dt = 0; dt < 4; ++dt)
            orow[(size_t)((g << 2) + rg) * D_MODEL + (dt << 4) + r] = oacc[dt][rg] * inv;
    }
}

// ---------------------------------------------------------------------------
extern "C" void kernel_launch(void* const* d_in, const int* in_sizes, int n_in,
                              void* d_out, int out_size, void* d_ws, size_t ws_size,
                              hipStream_t stream) {
    const float* x    = (const float*)d_in[0];
    const float* t    = (const float*)d_in[1];
    const float* cond = (const float*)d_in[2];
    const float* n1_w = (const float*)d_in[3];
    const float* n1_b = (const float*)d_in[4];
    const float* n2_w = (const float*)d_in[5];
    const float* n2_b = (const float*)d_in[6];
    const float* n4_w = (const float*)d_in[7];
    const float* n4_b = (const float*)d_in[8];
    const float* a1_q = (const float*)d_in[9];
    const float* a1_k = (const float*)d_in[10];
    const float* a1_v = (const float*)d_in[11];
    const float* a1_o = (const float*)d_in[12];
    const float* a1_ob= (const float*)d_in[13];
    const float* a2_q = (const float*)d_in[14];
    const float* a2_k = (const float*)d_in[15];
    const float* a2_v = (const float*)d_in[16];
    const float* a2_o = (const float*)d_in[17];
    const float* a2_ob= (const float*)d_in[18];
    const float* ff_w1= (const float*)d_in[19];
    const float* ff_b1= (const float*)d_in[20];
    const float* ff_w2= (const float*)d_in[21];
    const float* ff_b2= (const float*)d_in[22];
    float* out = (float*)d_out;

    const int B  = in_sizes[1] / D_MODEL;              // 2
    const int N  = in_sizes[0] / (B * D_MODEL);        // 2048
    const int Nc = in_sizes[2] / (B * D_MODEL);        // 1024
    const int R  = B * N;                              // 4096
    const int Rc = B * Nc;                             // 2048

    float* wsf = (float*)d_ws;
    float* emb = wsf;
    float* h   = emb + (size_t)3 * B * 2 * D_MODEL;
    float* qb  = h  + (size_t)R * D_MODEL;
    float* kb  = qb + (size_t)R * D_MODEL;
    float* vb  = kb + (size_t)R * D_MODEL;
    float* gg  = qb;   // GEGLU intermediate [R,2048]

    dim3 blk(256);

    adaln_params_kernel<<<dim3((3 * B * 2 * D_MODEL + 255) / 256), blk, 0, stream>>>(
        t, n1_w, n1_b, n2_w, n2_b, n4_w, n4_b, emb, B);

    // ---- block 1: self-attention ------------------------------------------
    adaln_apply_kernel<<<dim3(R), blk, 0, stream>>>(x, emb, h, N);
    gemm64_kernel<false, false><<<dim3(D_MODEL / 64, R / 64), blk, 0, stream>>>(
        h, a1_q, nullptr, nullptr, qb, R, D_MODEL, D_MODEL);
    gemm64_kernel<false, false><<<dim3(D_MODEL / 64, R / 64), blk, 0, stream>>>(
        h, a1_k, nullptr, nullptr, kb, R, D_MODEL, D_MODEL);
    gemm64_kernel<false, false><<<dim3(D_MODEL / 64, R / 64), blk, 0, stream>>>(
        h, a1_v, nullptr, nullptr, vb, R, D_MODEL, D_MODEL);
    attn_mfma_kernel<<<dim3(B * NHEADS * (N / 64)), blk, 0, stream>>>(qb, kb, vb, h, N, N);
    gemm64_kernel<true, true><<<dim3(D_MODEL / 64, R / 64), blk, 0, stream>>>(
        h, a1_o, a1_ob, x, out, R, D_MODEL, D_MODEL);

    // ---- block 2: cross-attention -----------------------------------------
    adaln_apply_kernel<<<dim3(R), blk, 0, stream>>>(out, emb + (size_t)B * 2 * D_MODEL, h, N);
    gemm64_kernel<false, false><<<dim3(D_MODEL / 64, R / 64), blk, 0, stream>>>(
        h, a2_q, nullptr, nullptr, qb, R, D_MODEL, D_MODEL);
    gemm64_kernel<false, false><<<dim3(D_MODEL / 64, Rc / 64), blk, 0, stream>>>(
        cond, a2_k, nullptr, nullptr, kb, Rc, D_MODEL, D_MODEL);
    gemm64_kernel<false, false><<<dim3(D_MODEL / 64, Rc / 64), blk, 0, stream>>>(
        cond, a2_v, nullptr, nullptr, vb, Rc, D_MODEL, D_MODEL);
    attn_mfma_kernel<<<dim3(B * NHEADS * (N / 64)), blk, 0, stream>>>(qb, kb, vb, h, N, Nc);
    gemm64_kernel<true, true><<<dim3(D_MODEL / 64, R / 64), blk, 0, stream>>>(
        h, a2_o, a2_ob, out, out, R, D_MODEL, D_MODEL);

    // ---- GEGLU feed-forward -------------------------------------------------
    adaln_apply_kernel<<<dim3(R), blk, 0, stream>>>(out, emb + (size_t)2 * B * 2 * D_MODEL, h, N);
    gemm_geglu_kernel<<<dim3((4 * D_MODEL) / 64, R / 64), blk, 0, stream>>>(
        h, ff_w1, ff_b1, gg, R, D_MODEL);
    gemm64_kernel<true, true><<<dim3(D_MODEL / 64, R / 64), blk, 0, stream>>>(
        gg, ff_w2, ff_b2, out, out, R, 4 * D_MODEL, D_MODEL);
}

// Round 3
// 316.020 us; speedup vs baseline: 12.5831x; 2.5009x over previous
//
#include <hip/hip_runtime.h>
#include <math.h>

#define D_MODEL 512
#define NHEADS  8
#define DHEAD   64

typedef __bf16  bf16x2 __attribute__((ext_vector_type(2)));
typedef __bf16  bf16x8 __attribute__((ext_vector_type(8)));
typedef float   f32x4  __attribute__((ext_vector_type(4)));

// ---------------------------------------------------------------------------
// emb = t @ W + b for the three AdaLN linears. Output layout: [norm][B][2D]
// ---------------------------------------------------------------------------
__global__ __launch_bounds__(256) void adaln_params_kernel(
        const float* __restrict__ t,
        const float* __restrict__ w1, const float* __restrict__ b1,
        const float* __restrict__ w2, const float* __restrict__ b2,
        const float* __restrict__ w4, const float* __restrict__ b4,
        float* __restrict__ emb, int B) {
    int g = blockIdx.x * blockDim.x + threadIdx.x;
    int per = B * 2 * D_MODEL;
    if (g >= 3 * per) return;
    int norm = g / per;
    int rem  = g - norm * per;
    int b = rem / (2 * D_MODEL);
    int c = rem % (2 * D_MODEL);
    const float* W  = (norm == 0) ? w1 : (norm == 1 ? w2 : w4);
    const float* bb = (norm == 0) ? b1 : (norm == 1 ? b2 : b4);
    const float* trow = t + (size_t)b * D_MODEL;
    float acc = bb[c];
    for (int k = 0; k < D_MODEL; ++k)
        acc = fmaf(trow[k], W[(size_t)k * (2 * D_MODEL) + c], acc);
    emb[g] = acc;
}

// ---------------------------------------------------------------------------
// AdaLN apply -> bf16 output. Block per row (512 cols, 2 per thread).
// ---------------------------------------------------------------------------
__global__ __launch_bounds__(256) void adaln_apply_kernel(
        const float* __restrict__ x, const float* __restrict__ emb_n,
        __bf16* __restrict__ h, int N) {
    int row = blockIdx.x;
    int b = row / N;
    const float* xr = x + (size_t)row * D_MODEL;
    int tid = threadIdx.x;
    float2 v = *(const float2*)(xr + 2 * tid);
    float s = v.x + v.y, sq = v.x * v.x + v.y * v.y;
#pragma unroll
    for (int off = 32; off; off >>= 1) {
        s  += __shfl_xor(s, off);
        sq += __shfl_xor(sq, off);
    }
    __shared__ float rs[4], rq[4];
    if ((tid & 63) == 0) { rs[tid >> 6] = s; rq[tid >> 6] = sq; }
    __syncthreads();
    float tot  = rs[0] + rs[1] + rs[2] + rs[3];
    float totq = rq[0] + rq[1] + rq[2] + rq[3];
    float mu  = tot * (1.0f / D_MODEL);
    float var = totq * (1.0f / D_MODEL) - mu * mu;
    float inv = rsqrtf(var + 1e-5f);
    const float* er = emb_n + (size_t)b * (2 * D_MODEL);
    float2 sc = *(const float2*)(er + 2 * tid);
    float2 sh = *(const float2*)(er + D_MODEL + 2 * tid);
    bf16x2 o;
    o[0] = (__bf16)((v.x - mu) * inv * (1.0f + sc.x) + sh.x);
    o[1] = (__bf16)((v.y - mu) * inv * (1.0f + sc.y) + sh.y);
    *(bf16x2*)(h + (size_t)row * D_MODEL + 2 * tid) = o;
}

// ---------------------------------------------------------------------------
// fp32 -> bf16 straight convert (n multiple of 4)
// ---------------------------------------------------------------------------
__global__ __launch_bounds__(256) void convert_bf16v_kernel(
        const float* __restrict__ src, __bf16* __restrict__ dst, int n) {
    int i = (blockIdx.x * 256 + threadIdx.x) * 4;
    if (i >= n) return;
    float4 v = *(const float4*)(src + i);
    bf16x2 a, b;
    a[0] = (__bf16)v.x; a[1] = (__bf16)v.y;
    b[0] = (__bf16)v.z; b[1] = (__bf16)v.w;
    *(bf16x2*)(dst + i)     = a;
    *(bf16x2*)(dst + i + 2) = b;
}

// ---------------------------------------------------------------------------
// Transpose+convert: src [K][N] fp32 -> dst [N][K] bf16.  64x64 LDS tile.
// ---------------------------------------------------------------------------
__device__ __forceinline__ void transpose_tile(
        const float* __restrict__ src, __bf16* __restrict__ dst,
        int K, int N, int k0, int n0) {
    __shared__ float t[64][65];
    int tid = threadIdx.x;
    int r = tid >> 6, c = tid & 63;
#pragma unroll
    for (int i = 0; i < 16; ++i)
        t[r + 4 * i][c] = src[(size_t)(k0 + r + 4 * i) * N + n0 + c];
    __syncthreads();
#pragma unroll
    for (int i = 0; i < 16; ++i)
        dst[(size_t)(n0 + r + 4 * i) * K + k0 + c] = (__bf16)t[c][r + 4 * i];
}

struct WPtrs8 { const float* s[8]; __bf16* d[8]; };

__global__ __launch_bounds__(256) void convt8_kernel(WPtrs8 p) {
    int w = blockIdx.z;
    transpose_tile(p.s[w], p.d[w], 512, 512, blockIdx.y * 64, blockIdx.x * 64);
}

__global__ __launch_bounds__(256) void convt_kernel(
        const float* __restrict__ src, __bf16* __restrict__ dst, int K, int N) {
    transpose_tile(src, dst, K, N, blockIdx.y * 64, blockIdx.x * 64);
}

// ---------------------------------------------------------------------------
// bf16 MFMA GEMM core. C = A[M,K] @ Bt[N,K]^T. 128x64 tile, BK=64, 4 waves.
// OUT=0: write bf16 (no bias/res). OUT=1: fp32 with bias+res.
// ---------------------------------------------------------------------------
template<int OUT>
__global__ __launch_bounds__(256) void gemm_bf16_kernel(
        const __bf16* __restrict__ A, const __bf16* __restrict__ Bt,
        const float* __restrict__ bias, const float* __restrict__ res,
        void* __restrict__ Cv, int M, int K, int N) {
    __shared__ __attribute__((aligned(16))) __bf16 As[128][72];
    __shared__ __attribute__((aligned(16))) __bf16 Bs[64][72];
    int tid = threadIdx.x;
    int wave = tid >> 6, lane = tid & 63;
    int wr = wave >> 1, wc = wave & 1;
    int r = lane & 15, g = lane >> 4;
    int m0 = blockIdx.y << 7, n0 = blockIdx.x << 6;

    int sr = tid >> 3, sk = (tid & 7) << 3;
    const __bf16* Ap = A  + (size_t)(m0 + sr) * K + sk;
    const __bf16* Bp = Bt + (size_t)(n0 + sr) * K + sk;

    f32x4 acc[4][2];
#pragma unroll
    for (int mi = 0; mi < 4; ++mi)
#pragma unroll
        for (int ni = 0; ni < 2; ++ni) acc[mi][ni] = (f32x4){0.f, 0.f, 0.f, 0.f};

    for (int k0 = 0; k0 < K; k0 += 64) {
#pragma unroll
        for (int i = 0; i < 4; ++i)
            *(bf16x8*)&As[sr + 32 * i][sk] = *(const bf16x8*)(Ap + (size_t)(32 * i) * K + k0);
#pragma unroll
        for (int i = 0; i < 2; ++i)
            *(bf16x8*)&Bs[sr + 32 * i][sk] = *(const bf16x8*)(Bp + (size_t)(32 * i) * K + k0);
        __syncthreads();
#pragma unroll
        for (int kk = 0; kk < 2; ++kk) {
            bf16x8 af[4], bfr[2];
#pragma unroll
            for (int mi = 0; mi < 4; ++mi)
                af[mi] = *(const bf16x8*)&As[(wr << 6) + (mi << 4) + r][(kk << 5) + (g << 3)];
#pragma unroll
            for (int ni = 0; ni < 2; ++ni)
                bfr[ni] = *(const bf16x8*)&Bs[(wc << 5) + (ni << 4) + r][(kk << 5) + (g << 3)];
#pragma unroll
            for (int mi = 0; mi < 4; ++mi)
#pragma unroll
                for (int ni = 0; ni < 2; ++ni)
                    acc[mi][ni] = __builtin_amdgcn_mfma_f32_16x16x32_bf16(
                        af[mi], bfr[ni], acc[mi][ni], 0, 0, 0);
        }
        __syncthreads();
    }

#pragma unroll
    for (int mi = 0; mi < 4; ++mi) {
#pragma unroll
        for (int ni = 0; ni < 2; ++ni) {
            int col = n0 + (wc << 5) + (ni << 4) + r;
#pragma unroll
            for (int rg = 0; rg < 4; ++rg) {
                int row = m0 + (wr << 6) + (mi << 4) + (g << 2) + rg;
                if (OUT == 0) {
                    ((__bf16*)Cv)[(size_t)row * N + col] = (__bf16)acc[mi][ni][rg];
                } else {
                    float v = acc[mi][ni][rg] + bias[col] + res[(size_t)row * N + col];
                    ((float*)Cv)[(size_t)row * N + col] = v;
                }
            }
        }
    }
}

// ---------------------------------------------------------------------------
// Fused GEGLU FF1 (bf16 MFMA): gg[M,2048] = u * gelu(g)
// ---------------------------------------------------------------------------
__global__ __launch_bounds__(256) void gemm_geglu_bf16_kernel(
        const __bf16* __restrict__ A, const __bf16* __restrict__ W1t,
        const float* __restrict__ b1, __bf16* __restrict__ gg, int M, int K) {
    const int NOUT = 4 * D_MODEL;   // 2048
    __shared__ __attribute__((aligned(16))) __bf16 As[128][72];
    __shared__ __attribute__((aligned(16))) __bf16 Bu[64][72];
    __shared__ __attribute__((aligned(16))) __bf16 Bg[64][72];
    int tid = threadIdx.x;
    int wave = tid >> 6, lane = tid & 63;
    int wr = wave >> 1, wc = wave & 1;
    int r = lane & 15, g = lane >> 4;
    int m0 = blockIdx.y << 7, n0 = blockIdx.x << 6;

    int sr = tid >> 3, sk = (tid & 7) << 3;
    const __bf16* Ap = A   + (size_t)(m0 + sr) * K + sk;
    const __bf16* Up = W1t + (size_t)(n0 + sr) * K + sk;
    const __bf16* Gp = W1t + (size_t)(NOUT + n0 + sr) * K + sk;

    f32x4 accu[4][2], accg[4][2];
#pragma unroll
    for (int mi = 0; mi < 4; ++mi)
#pragma unroll
        for (int ni = 0; ni < 2; ++ni) {
            accu[mi][ni] = (f32x4){0.f, 0.f, 0.f, 0.f};
            accg[mi][ni] = (f32x4){0.f, 0.f, 0.f, 0.f};
        }

    for (int k0 = 0; k0 < K; k0 += 64) {
#pragma unroll
        for (int i = 0; i < 4; ++i)
            *(bf16x8*)&As[sr + 32 * i][sk] = *(const bf16x8*)(Ap + (size_t)(32 * i) * K + k0);
#pragma unroll
        for (int i = 0; i < 2; ++i) {
            *(bf16x8*)&Bu[sr + 32 * i][sk] = *(const bf16x8*)(Up + (size_t)(32 * i) * K + k0);
            *(bf16x8*)&Bg[sr + 32 * i][sk] = *(const bf16x8*)(Gp + (size_t)(32 * i) * K + k0);
        }
        __syncthreads();
#pragma unroll
        for (int kk = 0; kk < 2; ++kk) {
            bf16x8 af[4], bu[2], bg[2];
#pragma unroll
            for (int mi = 0; mi < 4; ++mi)
                af[mi] = *(const bf16x8*)&As[(wr << 6) + (mi << 4) + r][(kk << 5) + (g << 3)];
#pragma unroll
            for (int ni = 0; ni < 2; ++ni) {
                bu[ni] = *(const bf16x8*)&Bu[(wc << 5) + (ni << 4) + r][(kk << 5) + (g << 3)];
                bg[ni] = *(const bf16x8*)&Bg[(wc << 5) + (ni << 4) + r][(kk << 5) + (g << 3)];
            }
#pragma unroll
            for (int mi = 0; mi < 4; ++mi)
#pragma unroll
                for (int ni = 0; ni < 2; ++ni) {
                    accu[mi][ni] = __builtin_amdgcn_mfma_f32_16x16x32_bf16(
                        af[mi], bu[ni], accu[mi][ni], 0, 0, 0);
                    accg[mi][ni] = __builtin_amdgcn_mfma_f32_16x16x32_bf16(
                        af[mi], bg[ni], accg[mi][ni], 0, 0, 0);
                }
        }
        __syncthreads();
    }

#pragma unroll
    for (int mi = 0; mi < 4; ++mi) {
#pragma unroll
        for (int ni = 0; ni < 2; ++ni) {
            int col = n0 + (wc << 5) + (ni << 4) + r;
            float bu_ = b1[col], bg_ = b1[NOUT + col];
#pragma unroll
            for (int rg = 0; rg < 4; ++rg) {
                int row = m0 + (wr << 6) + (mi << 4) + (g << 2) + rg;
                float u  = accu[mi][ni][rg] + bu_;
                float gv = accg[mi][ni][rg] + bg_;
                float ge = 0.5f * gv * (1.0f + erff(gv * 0.70710678118654752f));
                gg[(size_t)row * NOUT + col] = (__bf16)(u * ge);
            }
        }
    }
}

// ---------------------------------------------------------------------------
// bf16 MFMA flash attention (bf16 in / bf16 out).
// ---------------------------------------------------------------------------
__global__ __launch_bounds__(256) void attn_mfma_kernel(
        const __bf16* __restrict__ q, const __bf16* __restrict__ k,
        const __bf16* __restrict__ v, __bf16* __restrict__ o,
        int Nq, int Nk) {
    __shared__ __attribute__((aligned(16))) __bf16 Ks[64][72];
    __shared__ __attribute__((aligned(16))) __bf16 Vt[64][72];
    __shared__ __attribute__((aligned(16))) __bf16 Pl[4][16][72];

    int tid = threadIdx.x;
    int w = tid >> 6, lane = tid & 63;
    int r = lane & 15, g = lane >> 4;

    int nqb = Nq >> 6;
    int qb = blockIdx.x % nqb;
    int hh = (blockIdx.x / nqb) % NHEADS;
    int b  = blockIdx.x / (nqb * NHEADS);

    const __bf16* qp = q + ((size_t)(b * Nq + (qb << 6) + (w << 4) + r)) * D_MODEL
                         + hh * DHEAD + (g << 3);
    bf16x8 qf[2] = { *(const bf16x8*)qp, *(const bf16x8*)(qp + 32) };

    f32x4 oacc[4];
#pragma unroll
    for (int dt = 0; dt < 4; ++dt) oacc[dt] = (f32x4){0.f, 0.f, 0.f, 0.f};
    float m_r[4] = {-1e30f, -1e30f, -1e30f, -1e30f};
    float l_r[4] = {0.f, 0.f, 0.f, 0.f};

    size_t kvbase = (size_t)b * Nk * D_MODEL + (size_t)hh * DHEAD;

    for (int kb = 0; kb < Nk; kb += 64) {
        if (kb) __syncthreads();
        {
            int row = tid >> 2, cb = (tid & 3) << 4;
            const __bf16* src = k + kvbase + (size_t)(kb + row) * D_MODEL + cb;
            *(bf16x8*)&Ks[row][cb]     = *(const bf16x8*)src;
            *(bf16x8*)&Ks[row][cb + 8] = *(const bf16x8*)(src + 8);
        }
        {
            int key = tid >> 2, db = (tid & 3) << 4;
            const __bf16* src = v + kvbase + (size_t)(kb + key) * D_MODEL + db;
#pragma unroll
            for (int i = 0; i < 16; ++i) Vt[db + i][key] = src[i];
        }
        __syncthreads();

        f32x4 sacc[4];
#pragma unroll
        for (int nt = 0; nt < 4; ++nt) sacc[nt] = (f32x4){0.f, 0.f, 0.f, 0.f};
#pragma unroll
        for (int nt = 0; nt < 4; ++nt) {
            bf16x8 k0 = *(const bf16x8*)&Ks[(nt << 4) + r][g << 3];
            bf16x8 k1 = *(const bf16x8*)&Ks[(nt << 4) + r][32 + (g << 3)];
            sacc[nt] = __builtin_amdgcn_mfma_f32_16x16x32_bf16(qf[0], k0, sacc[nt], 0, 0, 0);
            sacc[nt] = __builtin_amdgcn_mfma_f32_16x16x32_bf16(qf[1], k1, sacc[nt], 0, 0, 0);
        }
#pragma unroll
        for (int nt = 0; nt < 4; ++nt)
#pragma unroll
            for (int rg = 0; rg < 4; ++rg) sacc[nt][rg] *= 0.125f;

#pragma unroll
        for (int rg = 0; rg < 4; ++rg) {
            float mx = fmaxf(fmaxf(sacc[0][rg], sacc[1][rg]),
                             fmaxf(sacc[2][rg], sacc[3][rg]));
#pragma unroll
            for (int off = 1; off < 16; off <<= 1) mx = fmaxf(mx, __shfl_xor(mx, off));
            float mn = fmaxf(m_r[rg], mx);
            float al = __expf(m_r[rg] - mn);
            m_r[rg] = mn;
            float sum = 0.f;
#pragma unroll
            for (int nt = 0; nt < 4; ++nt) {
                float p = __expf(sacc[nt][rg] - mn);
                sum += p;
                Pl[w][(g << 2) + rg][(nt << 4) + r] = (__bf16)p;
            }
#pragma unroll
            for (int off = 1; off < 16; off <<= 1) sum += __shfl_xor(sum, off);
            l_r[rg] = l_r[rg] * al + sum;
#pragma unroll
            for (int dt = 0; dt < 4; ++dt) oacc[dt][rg] *= al;
        }

#pragma unroll
        for (int kh = 0; kh < 2; ++kh) {
            bf16x8 pa = *(const bf16x8*)&Pl[w][r][(kh << 5) + (g << 3)];
#pragma unroll
            for (int dt = 0; dt < 4; ++dt) {
                bf16x8 vb = *(const bf16x8*)&Vt[(dt << 4) + r][(kh << 5) + (g << 3)];
                oacc[dt] = __builtin_amdgcn_mfma_f32_16x16x32_bf16(pa, vb, oacc[dt], 0, 0, 0);
            }
        }
    }

    __bf16* orow = o + ((size_t)(b * Nq + (qb << 6) + (w << 4))) * D_MODEL + hh * DHEAD;
#pragma unroll
    for (int rg = 0; rg < 4; ++rg) {
        float inv = 1.0f / l_r[rg];
#pragma unroll
        for (int dt = 0; dt < 4; ++dt)
            orow[(size_t)((g << 2) + rg) * D_MODEL + (dt << 4) + r] =
                (__bf16)(oacc[dt][rg] * inv);
    }
}

// ---------------------------------------------------------------------------
extern "C" void kernel_launch(void* const* d_in, const int* in_sizes, int n_in,
                              void* d_out, int out_size, void* d_ws, size_t ws_size,
                              hipStream_t stream) {
    const float* x    = (const float*)d_in[0];
    const float* t    = (const float*)d_in[1];
    const float* cond = (const float*)d_in[2];
    const float* n1_w = (const float*)d_in[3];
    const float* n1_b = (const float*)d_in[4];
    const float* n2_w = (const float*)d_in[5];
    const float* n2_b = (const float*)d_in[6];
    const float* n4_w = (const float*)d_in[7];
    const float* n4_b = (const float*)d_in[8];
    const float* a1_q = (const float*)d_in[9];
    const float* a1_k = (const float*)d_in[10];
    const float* a1_v = (const float*)d_in[11];
    const float* a1_o = (const float*)d_in[12];
    const float* a1_ob= (const float*)d_in[13];
    const float* a2_q = (const float*)d_in[14];
    const float* a2_k = (const float*)d_in[15];
    const float* a2_v = (const float*)d_in[16];
    const float* a2_o = (const float*)d_in[17];
    const float* a2_ob= (const float*)d_in[18];
    const float* ff_w1= (const float*)d_in[19];
    const float* ff_b1= (const float*)d_in[20];
    const float* ff_w2= (const float*)d_in[21];
    const float* ff_b2= (const float*)d_in[22];
    float* out = (float*)d_out;

    const int B  = in_sizes[1] / D_MODEL;              // 2
    const int N  = in_sizes[0] / (B * D_MODEL);        // 2048
    const int Nc = in_sizes[2] / (B * D_MODEL);        // 1024
    const int R  = B * N;                              // 4096
    const int Rc = B * Nc;                             // 2048

    // ---- workspace layout (~30.3 MB) ----------------------------------------
    char* Wb = (char*)d_ws;
    float* emb   = (float*)Wb;                                  // 24 KB (pad 32 KB)
    __bf16* r1   = (__bf16*)(Wb + 32768);                       // 16 MB region
    __bf16* q_bf = r1;                                          // 4 MB
    __bf16* k_bf = r1 + (size_t)2097152;                        // 4 MB
    __bf16* v_bf = r1 + (size_t)2 * 2097152;                    // 4 MB
    __bf16* c_bf = r1 + (size_t)3 * 2097152;                    // 2 MB (cond)
    __bf16* gg   = r1;                                          // 16 MB (aliases)
    __bf16* h_bf = (__bf16*)(Wb + 32768 + 16777216);            // 4 MB (also attn out)
    __bf16* wts  = (__bf16*)(Wb + 32768 + 16777216 + 4194304);  // 10 MB
    __bf16* a1_qt = wts;
    __bf16* a1_kt = wts + 262144;
    __bf16* a1_vt = wts + 2 * 262144;
    __bf16* a1_ot = wts + 3 * 262144;
    __bf16* a2_qt = wts + 4 * 262144;
    __bf16* a2_kt = wts + 5 * 262144;
    __bf16* a2_vt = wts + 6 * 262144;
    __bf16* a2_ot = wts + 7 * 262144;
    __bf16* ff1t  = wts + 8 * 262144;            // [4096][512]
    __bf16* ff2t  = ff1t + 2097152;              // [512][2048]

    dim3 blk(256);

    // ---- prep ----------------------------------------------------------------
    adaln_params_kernel<<<dim3((3 * B * 2 * D_MODEL + 255) / 256), blk, 0, stream>>>(
        t, n1_w, n1_b, n2_w, n2_b, n4_w, n4_b, emb, B);

    WPtrs8 wp;
    wp.s[0] = a1_q; wp.s[1] = a1_k; wp.s[2] = a1_v; wp.s[3] = a1_o;
    wp.s[4] = a2_q; wp.s[5] = a2_k; wp.s[6] = a2_v; wp.s[7] = a2_o;
    wp.d[0] = a1_qt; wp.d[1] = a1_kt; wp.d[2] = a1_vt; wp.d[3] = a1_ot;
    wp.d[4] = a2_qt; wp.d[5] = a2_kt; wp.d[6] = a2_vt; wp.d[7] = a2_ot;
    convt8_kernel<<<dim3(8, 8, 8), blk, 0, stream>>>(wp);
    convt_kernel<<<dim3(64, 8), blk, 0, stream>>>(ff_w1, ff1t, 512, 4096);
    convt_kernel<<<dim3(8, 32), blk, 0, stream>>>(ff_w2, ff2t, 2048, 512);
    convert_bf16v_kernel<<<dim3(Rc * D_MODEL / 1024), blk, 0, stream>>>(
        cond, c_bf, Rc * D_MODEL);

    // ---- block 1: self-attention ----------------------------------------------
    adaln_apply_kernel<<<dim3(R), blk, 0, stream>>>(x, emb, h_bf, N);
    gemm_bf16_kernel<0><<<dim3(8, R / 128), blk, 0, stream>>>(
        h_bf, a1_qt, nullptr, nullptr, q_bf, R, 512, 512);
    gemm_bf16_kernel<0><<<dim3(8, R / 128), blk, 0, stream>>>(
        h_bf, a1_kt, nullptr, nullptr, k_bf, R, 512, 512);
    gemm_bf16_kernel<0><<<dim3(8, R / 128), blk, 0, stream>>>(
        h_bf, a1_vt, nullptr, nullptr, v_bf, R, 512, 512);
    attn_mfma_kernel<<<dim3(B * NHEADS * (N / 64)), blk, 0, stream>>>(
        q_bf, k_bf, v_bf, h_bf, N, N);
    gemm_bf16_kernel<1><<<dim3(8, R / 128), blk, 0, stream>>>(
        h_bf, a1_ot, a1_ob, x, out, R, 512, 512);

    // ---- block 2: cross-attention ----------------------------------------------
    adaln_apply_kernel<<<dim3(R), blk, 0, stream>>>(
        out, emb + (size_t)B * 2 * D_MODEL, h_bf, N);
    gemm_bf16_kernel<0><<<dim3(8, R / 128), blk, 0, stream>>>(
        h_bf, a2_qt, nullptr, nullptr, q_bf, R, 512, 512);
    gemm_bf16_kernel<0><<<dim3(8, Rc / 128), blk, 0, stream>>>(
        c_bf, a2_kt, nullptr, nullptr, k_bf, Rc, 512, 512);
    gemm_bf16_kernel<0><<<dim3(8, Rc / 128), blk, 0, stream>>>(
        c_bf, a2_vt, nullptr, nullptr, v_bf, Rc, 512, 512);
    attn_mfma_kernel<<<dim3(B * NHEADS * (N / 64)), blk, 0, stream>>>(
        q_bf, k_bf, v_bf, h_bf, N, Nc);
    gemm_bf16_kernel<1><<<dim3(8, R / 128), blk, 0, stream>>>(
        h_bf, a2_ot, a2_ob, out, out, R, 512, 512);

    // ---- GEGLU feed-forward -------------------------------------------------------
    adaln_apply_kernel<<<dim3(R), blk, 0, stream>>>(
        out, emb + (size_t)2 * B * 2 * D_MODEL, h_bf, N);
    gemm_geglu_bf16_kernel<<<dim3(32, R / 128), blk, 0, stream>>>(
        h_bf, ff1t, ff_b1, gg, R, 512);
    gemm_bf16_kernel<1><<<dim3(8, R / 128), blk, 0, stream>>>(
        gg, ff2t, ff_b2, out, out, R, 2048, 512);
}

// Round 4
// 251.448 us; speedup vs baseline: 15.8144x; 1.2568x over previous
//
#include <hip/hip_runtime.h>
#include <math.h>

#define D_MODEL 512
#define NHEADS  8
#define DHEAD   64

typedef __bf16  bf16x2 __attribute__((ext_vector_type(2)));
typedef __bf16  bf16x4 __attribute__((ext_vector_type(4)));
typedef __bf16  bf16x8 __attribute__((ext_vector_type(8)));
typedef float   f32x4  __attribute__((ext_vector_type(4)));

// ---------------------------------------------------------------------------
// emb = t @ W + b for the three AdaLN linears. Output layout: [norm][B][2D]
// ---------------------------------------------------------------------------
__global__ __launch_bounds__(256) void adaln_params_kernel(
        const float* __restrict__ t,
        const float* __restrict__ w1, const float* __restrict__ b1,
        const float* __restrict__ w2, const float* __restrict__ b2,
        const float* __restrict__ w4, const float* __restrict__ b4,
        float* __restrict__ emb, int B) {
    int g = blockIdx.x * blockDim.x + threadIdx.x;
    int per = B * 2 * D_MODEL;
    if (g >= 3 * per) return;
    int norm = g / per;
    int rem  = g - norm * per;
    int b = rem / (2 * D_MODEL);
    int c = rem % (2 * D_MODEL);
    const float* W  = (norm == 0) ? w1 : (norm == 1 ? w2 : w4);
    const float* bb = (norm == 0) ? b1 : (norm == 1 ? b2 : b4);
    const float* trow = t + (size_t)b * D_MODEL;
    float acc = bb[c];
    for (int k = 0; k < D_MODEL; ++k)
        acc = fmaf(trow[k], W[(size_t)k * (2 * D_MODEL) + c], acc);
    emb[g] = acc;
}

// ---------------------------------------------------------------------------
// AdaLN apply -> bf16 output. Block per row (512 cols, 2 per thread).
// ---------------------------------------------------------------------------
__global__ __launch_bounds__(256) void adaln_apply_kernel(
        const float* __restrict__ x, const float* __restrict__ emb_n,
        __bf16* __restrict__ h, int N) {
    int row = blockIdx.x;
    int b = row / N;
    const float* xr = x + (size_t)row * D_MODEL;
    int tid = threadIdx.x;
    float2 v = *(const float2*)(xr + 2 * tid);
    float s = v.x + v.y, sq = v.x * v.x + v.y * v.y;
#pragma unroll
    for (int off = 32; off; off >>= 1) {
        s  += __shfl_xor(s, off);
        sq += __shfl_xor(sq, off);
    }
    __shared__ float rs[4], rq[4];
    if ((tid & 63) == 0) { rs[tid >> 6] = s; rq[tid >> 6] = sq; }
    __syncthreads();
    float tot  = rs[0] + rs[1] + rs[2] + rs[3];
    float totq = rq[0] + rq[1] + rq[2] + rq[3];
    float mu  = tot * (1.0f / D_MODEL);
    float var = totq * (1.0f / D_MODEL) - mu * mu;
    float inv = rsqrtf(var + 1e-5f);
    const float* er = emb_n + (size_t)b * (2 * D_MODEL);
    float2 sc = *(const float2*)(er + 2 * tid);
    float2 sh = *(const float2*)(er + D_MODEL + 2 * tid);
    bf16x2 o;
    o[0] = (__bf16)((v.x - mu) * inv * (1.0f + sc.x) + sh.x);
    o[1] = (__bf16)((v.y - mu) * inv * (1.0f + sc.y) + sh.y);
    *(bf16x2*)(h + (size_t)row * D_MODEL + 2 * tid) = o;
}

// ---------------------------------------------------------------------------
// fp32 -> bf16 straight convert (n multiple of 4)
// ---------------------------------------------------------------------------
__global__ __launch_bounds__(256) void convert_bf16v_kernel(
        const float* __restrict__ src, __bf16* __restrict__ dst, int n) {
    int i = (blockIdx.x * 256 + threadIdx.x) * 4;
    if (i >= n) return;
    float4 v = *(const float4*)(src + i);
    bf16x2 a, b;
    a[0] = (__bf16)v.x; a[1] = (__bf16)v.y;
    b[0] = (__bf16)v.z; b[1] = (__bf16)v.w;
    *(bf16x2*)(dst + i)     = a;
    *(bf16x2*)(dst + i + 2) = b;
}

// ---------------------------------------------------------------------------
// Transpose+convert: src [K][N] fp32 -> dst [N][K] bf16.  64x64 LDS tile.
// ---------------------------------------------------------------------------
__device__ __forceinline__ void transpose_tile(
        const float* __restrict__ src, __bf16* __restrict__ dst,
        int K, int N, int k0, int n0) {
    __shared__ float t[64][65];
    int tid = threadIdx.x;
    int r = tid >> 6, c = tid & 63;
#pragma unroll
    for (int i = 0; i < 16; ++i)
        t[r + 4 * i][c] = src[(size_t)(k0 + r + 4 * i) * N + n0 + c];
    __syncthreads();
#pragma unroll
    for (int i = 0; i < 16; ++i)
        dst[(size_t)(n0 + r + 4 * i) * K + k0 + c] = (__bf16)t[c][r + 4 * i];
}

struct WPtrs8 { const float* s[8]; __bf16* d[8]; };

__global__ __launch_bounds__(256) void convt8_kernel(WPtrs8 p) {
    int w = blockIdx.z;
    transpose_tile(p.s[w], p.d[w], 512, 512, blockIdx.y * 64, blockIdx.x * 64);
}

__global__ __launch_bounds__(256) void convt_kernel(
        const float* __restrict__ src, __bf16* __restrict__ dst, int K, int N) {
    transpose_tile(src, dst, K, N, blockIdx.y * 64, blockIdx.x * 64);
}

// ---------------------------------------------------------------------------
// bf16 MFMA GEMM core. C = A[M,K] @ Bt[N,K]^T. 128x64 tile, BK=64, 4 waves.
// OUT=0: write bf16. OUT=1: fp32 with bias+res. OUT=2: bf16, cols<512 *0.125.
// ---------------------------------------------------------------------------
template<int OUT>
__global__ __launch_bounds__(256) void gemm_bf16_kernel(
        const __bf16* __restrict__ A, const __bf16* __restrict__ Bt,
        const float* __restrict__ bias, const float* __restrict__ res,
        void* __restrict__ Cv, int M, int K, int N) {
    __shared__ __attribute__((aligned(16))) __bf16 As[128][72];
    __shared__ __attribute__((aligned(16))) __bf16 Bs[64][72];
    int tid = threadIdx.x;
    int wave = tid >> 6, lane = tid & 63;
    int wr = wave >> 1, wc = wave & 1;
    int r = lane & 15, g = lane >> 4;
    int m0 = blockIdx.y << 7, n0 = blockIdx.x << 6;

    int sr = tid >> 3, sk = (tid & 7) << 3;
    const __bf16* Ap = A  + (size_t)(m0 + sr) * K + sk;
    const __bf16* Bp = Bt + (size_t)(n0 + sr) * K + sk;

    f32x4 acc[4][2];
#pragma unroll
    for (int mi = 0; mi < 4; ++mi)
#pragma unroll
        for (int ni = 0; ni < 2; ++ni) acc[mi][ni] = (f32x4){0.f, 0.f, 0.f, 0.f};

    for (int k0 = 0; k0 < K; k0 += 64) {
#pragma unroll
        for (int i = 0; i < 4; ++i)
            *(bf16x8*)&As[sr + 32 * i][sk] = *(const bf16x8*)(Ap + (size_t)(32 * i) * K + k0);
#pragma unroll
        for (int i = 0; i < 2; ++i)
            *(bf16x8*)&Bs[sr + 32 * i][sk] = *(const bf16x8*)(Bp + (size_t)(32 * i) * K + k0);
        __syncthreads();
#pragma unroll
        for (int kk = 0; kk < 2; ++kk) {
            bf16x8 af[4], bfr[2];
#pragma unroll
            for (int mi = 0; mi < 4; ++mi)
                af[mi] = *(const bf16x8*)&As[(wr << 6) + (mi << 4) + r][(kk << 5) + (g << 3)];
#pragma unroll
            for (int ni = 0; ni < 2; ++ni)
                bfr[ni] = *(const bf16x8*)&Bs[(wc << 5) + (ni << 4) + r][(kk << 5) + (g << 3)];
#pragma unroll
            for (int mi = 0; mi < 4; ++mi)
#pragma unroll
                for (int ni = 0; ni < 2; ++ni)
                    acc[mi][ni] = __builtin_amdgcn_mfma_f32_16x16x32_bf16(
                        af[mi], bfr[ni], acc[mi][ni], 0, 0, 0);
        }
        __syncthreads();
    }

#pragma unroll
    for (int mi = 0; mi < 4; ++mi) {
#pragma unroll
        for (int ni = 0; ni < 2; ++ni) {
            int col = n0 + (wc << 5) + (ni << 4) + r;
            float scl = (OUT == 2 && col < 512) ? 0.125f : 1.0f;
#pragma unroll
            for (int rg = 0; rg < 4; ++rg) {
                int row = m0 + (wr << 6) + (mi << 4) + (g << 2) + rg;
                if (OUT == 1) {
                    float v = acc[mi][ni][rg] + bias[col] + res[(size_t)row * N + col];
                    ((float*)Cv)[(size_t)row * N + col] = v;
                } else {
                    ((__bf16*)Cv)[(size_t)row * N + col] = (__bf16)(acc[mi][ni][rg] * scl);
                }
            }
        }
    }
}

// ---------------------------------------------------------------------------
// Fused GEGLU FF1 (bf16 MFMA): gg[M,2048] = u * gelu(g)
// ---------------------------------------------------------------------------
__global__ __launch_bounds__(256) void gemm_geglu_bf16_kernel(
        const __bf16* __restrict__ A, const __bf16* __restrict__ W1t,
        const float* __restrict__ b1, __bf16* __restrict__ gg, int M, int K) {
    const int NOUT = 4 * D_MODEL;   // 2048
    __shared__ __attribute__((aligned(16))) __bf16 As[128][72];
    __shared__ __attribute__((aligned(16))) __bf16 Bu[64][72];
    __shared__ __attribute__((aligned(16))) __bf16 Bg[64][72];
    int tid = threadIdx.x;
    int wave = tid >> 6, lane = tid & 63;
    int wr = wave >> 1, wc = wave & 1;
    int r = lane & 15, g = lane >> 4;
    int m0 = blockIdx.y << 7, n0 = blockIdx.x << 6;

    int sr = tid >> 3, sk = (tid & 7) << 3;
    const __bf16* Ap = A   + (size_t)(m0 + sr) * K + sk;
    const __bf16* Up = W1t + (size_t)(n0 + sr) * K + sk;
    const __bf16* Gp = W1t + (size_t)(NOUT + n0 + sr) * K + sk;

    f32x4 accu[4][2], accg[4][2];
#pragma unroll
    for (int mi = 0; mi < 4; ++mi)
#pragma unroll
        for (int ni = 0; ni < 2; ++ni) {
            accu[mi][ni] = (f32x4){0.f, 0.f, 0.f, 0.f};
            accg[mi][ni] = (f32x4){0.f, 0.f, 0.f, 0.f};
        }

    for (int k0 = 0; k0 < K; k0 += 64) {
#pragma unroll
        for (int i = 0; i < 4; ++i)
            *(bf16x8*)&As[sr + 32 * i][sk] = *(const bf16x8*)(Ap + (size_t)(32 * i) * K + k0);
#pragma unroll
        for (int i = 0; i < 2; ++i) {
            *(bf16x8*)&Bu[sr + 32 * i][sk] = *(const bf16x8*)(Up + (size_t)(32 * i) * K + k0);
            *(bf16x8*)&Bg[sr + 32 * i][sk] = *(const bf16x8*)(Gp + (size_t)(32 * i) * K + k0);
        }
        __syncthreads();
#pragma unroll
        for (int kk = 0; kk < 2; ++kk) {
            bf16x8 af[4], bu[2], bg[2];
#pragma unroll
            for (int mi = 0; mi < 4; ++mi)
                af[mi] = *(const bf16x8*)&As[(wr << 6) + (mi << 4) + r][(kk << 5) + (g << 3)];
#pragma unroll
            for (int ni = 0; ni < 2; ++ni) {
                bu[ni] = *(const bf16x8*)&Bu[(wc << 5) + (ni << 4) + r][(kk << 5) + (g << 3)];
                bg[ni] = *(const bf16x8*)&Bg[(wc << 5) + (ni << 4) + r][(kk << 5) + (g << 3)];
            }
#pragma unroll
            for (int mi = 0; mi < 4; ++mi)
#pragma unroll
                for (int ni = 0; ni < 2; ++ni) {
                    accu[mi][ni] = __builtin_amdgcn_mfma_f32_16x16x32_bf16(
                        af[mi], bu[ni], accu[mi][ni], 0, 0, 0);
                    accg[mi][ni] = __builtin_amdgcn_mfma_f32_16x16x32_bf16(
                        af[mi], bg[ni], accg[mi][ni], 0, 0, 0);
                }
        }
        __syncthreads();
    }

#pragma unroll
    for (int mi = 0; mi < 4; ++mi) {
#pragma unroll
        for (int ni = 0; ni < 2; ++ni) {
            int col = n0 + (wc << 5) + (ni << 4) + r;
            float bu_ = b1[col], bg_ = b1[NOUT + col];
#pragma unroll
            for (int rg = 0; rg < 4; ++rg) {
                int row = m0 + (wr << 6) + (mi << 4) + (g << 2) + rg;
                float u  = accu[mi][ni][rg] + bu_;
                float gv = accg[mi][ni][rg] + bg_;
                float ge = 0.5f * gv * (1.0f + erff(gv * 0.70710678118654752f));
                gg[(size_t)row * NOUT + col] = (__bf16)(u * ge);
            }
        }
    }
}

// ---------------------------------------------------------------------------
// bf16 MFMA flash attention, swapped-operand form.
// QK^T: mfma(A=K, B=Q) -> S^T[key][qrow]: lane owns qrow = lane&15, 16 keys.
// Softmax fully per-lane (+2 shuffles across the 4 lane-groups).
// PV: mfma(A=V^T, B=P-frag from Pl[qrow][key]) -> O^T[dim][qrow].
// Q assumed pre-scaled by 1/sqrt(d) (folded into projection GEMM).
// Vt staged with (row>>3) XOR swizzle on 16B blocks; register prefetch of
// next K/V tile; setprio around MFMA clusters.
// ---------------------------------------------------------------------------
__global__ __launch_bounds__(256) void attn_mfma_kernel(
        const __bf16* __restrict__ q, const __bf16* __restrict__ k,
        const __bf16* __restrict__ v, __bf16* __restrict__ o,
        int Nq, int Nk, int sq, int skv) {
    __shared__ __attribute__((aligned(16))) __bf16 Ks[64][72];
    __shared__ __attribute__((aligned(16))) __bf16 Vt[64 * 72];   // swizzled
    __shared__ __attribute__((aligned(16))) __bf16 Pl[4][16][72];

    int tid = threadIdx.x;
    int w = tid >> 6, lane = tid & 63;
    int r = lane & 15, g = lane >> 4;

    int nqb = Nq >> 6;
    int qb = blockIdx.x % nqb;
    int hh = (blockIdx.x / nqb) % NHEADS;
    int b  = blockIdx.x / (nqb * NHEADS);

    // Q B-fragment (pre-scaled): lane holds Q[qrow=r][g*8.. ] per k-half
    const __bf16* qp = q + ((size_t)(b * Nq + (qb << 6) + (w << 4) + r)) * sq
                         + hh * DHEAD + (g << 3);
    bf16x8 qf0 = *(const bf16x8*)qp;
    bf16x8 qf1 = *(const bf16x8*)(qp + 32);

    // staging maps
    int krow = tid >> 2, kcb = (tid & 3) << 4;        // K: 32B of one key row
    int va = tid & 31,  vbb = tid >> 5;               // V: keys 2va,2va+1 dims 8vbb..
    size_t kvbase = (size_t)b * Nk * skv + (size_t)hh * DHEAD;
    const __bf16* kp = k + kvbase + (size_t)krow * skv + kcb;
    const __bf16* vp = v + kvbase + (size_t)(2 * va) * skv + (vbb << 3);

    f32x4 oacc[4];
#pragma unroll
    for (int dt = 0; dt < 4; ++dt) oacc[dt] = (f32x4){0.f, 0.f, 0.f, 0.f};
    float m = -1e30f, l = 0.f;

    // ---- stage tile 0 --------------------------------------------------------
    bf16x8 kr0 = *(const bf16x8*)kp;
    bf16x8 kr1 = *(const bf16x8*)(kp + 8);
    bf16x8 vr0 = *(const bf16x8*)vp;
    bf16x8 vr1 = *(const bf16x8*)(vp + skv);
    {
        *(bf16x8*)&Ks[krow][kcb]     = kr0;
        *(bf16x8*)&Ks[krow][kcb + 8] = kr1;
        int blk = (va >> 2) ^ vbb;
        int cw  = ((va & 3) << 1);
#pragma unroll
        for (int j = 0; j < 8; ++j) {
            bf16x2 pr; pr[0] = vr0[j]; pr[1] = vr1[j];
            *(bf16x2*)&Vt[(size_t)(8 * vbb + j) * 72 + blk * 8 + cw] = pr;
        }
    }
    __syncthreads();

    int ntiles = Nk >> 6;
    for (int t = 0; t < ntiles; ++t) {
        bool pre = (t + 1 < ntiles);
        if (pre) {
            const __bf16* kp2 = kp + (size_t)(t + 1) * 64 * skv;
            const __bf16* vp2 = vp + (size_t)(t + 1) * 64 * skv;
            kr0 = *(const bf16x8*)kp2;
            kr1 = *(const bf16x8*)(kp2 + 8);
            vr0 = *(const bf16x8*)vp2;
            vr1 = *(const bf16x8*)(vp2 + skv);
        }

        // ---- S^T = K Q^T ------------------------------------------------------
        f32x4 sacc[4];
#pragma unroll
        for (int nt = 0; nt < 4; ++nt) sacc[nt] = (f32x4){0.f, 0.f, 0.f, 0.f};
        __builtin_amdgcn_s_setprio(1);
#pragma unroll
        for (int nt = 0; nt < 4; ++nt) {
            bf16x8 kf0 = *(const bf16x8*)&Ks[(nt << 4) + r][g << 3];
            bf16x8 kf1 = *(const bf16x8*)&Ks[(nt << 4) + r][32 + (g << 3)];
            sacc[nt] = __builtin_amdgcn_mfma_f32_16x16x32_bf16(kf0, qf0, sacc[nt], 0, 0, 0);
            sacc[nt] = __builtin_amdgcn_mfma_f32_16x16x32_bf16(kf1, qf1, sacc[nt], 0, 0, 0);
        }
        __builtin_amdgcn_s_setprio(0);

        // ---- in-register online softmax (qrow = r, 16 keys per lane) ----------
        float mx = sacc[0][0];
#pragma unroll
        for (int nt = 0; nt < 4; ++nt)
#pragma unroll
            for (int rg = 0; rg < 4; ++rg) mx = fmaxf(mx, sacc[nt][rg]);
        mx = fmaxf(mx, __shfl_xor(mx, 16));
        mx = fmaxf(mx, __shfl_xor(mx, 32));
        float mn = fmaxf(m, mx);
        float al = __expf(m - mn);
        m = mn;
        float sum = 0.f;
#pragma unroll
        for (int nt = 0; nt < 4; ++nt) {
            bf16x4 pk;
#pragma unroll
            for (int rg = 0; rg < 4; ++rg) {
                float p = __expf(sacc[nt][rg] - mn);
                sum += p;
                pk[rg] = (__bf16)p;
            }
            *(bf16x4*)&Pl[w][r][(nt << 4) + (g << 2)] = pk;
        }
        sum += __shfl_xor(sum, 16);
        sum += __shfl_xor(sum, 32);
        l = l * al + sum;
#pragma unroll
        for (int dt = 0; dt < 4; ++dt)
#pragma unroll
            for (int rg = 0; rg < 4; ++rg) oacc[dt][rg] *= al;

        // ---- O^T += V^T P^T ----------------------------------------------------
        __builtin_amdgcn_s_setprio(1);
#pragma unroll
        for (int kh = 0; kh < 2; ++kh) {
            bf16x8 pa = *(const bf16x8*)&Pl[w][r][(kh << 5) + (g << 3)];
#pragma unroll
            for (int dt = 0; dt < 4; ++dt) {
                int row = (dt << 4) + r;
                int blk = ((kh << 2) + g) ^ ((row >> 3) & 7);
                bf16x8 vf = *(const bf16x8*)&Vt[(size_t)row * 72 + (blk << 3)];
                oacc[dt] = __builtin_amdgcn_mfma_f32_16x16x32_bf16(vf, pa, oacc[dt], 0, 0, 0);
            }
        }
        __builtin_amdgcn_s_setprio(0);

        __syncthreads();
        if (pre) {
            *(bf16x8*)&Ks[krow][kcb]     = kr0;
            *(bf16x8*)&Ks[krow][kcb + 8] = kr1;
            int blk = (va >> 2) ^ vbb;
            int cw  = ((va & 3) << 1);
#pragma unroll
            for (int j = 0; j < 8; ++j) {
                bf16x2 pr; pr[0] = vr0[j]; pr[1] = vr1[j];
                *(bf16x2*)&Vt[(size_t)(8 * vbb + j) * 72 + blk * 8 + cw] = pr;
            }
        }
        __syncthreads();
    }

    // ---- epilogue: O^T/l -> o[qrow][dim] -------------------------------------
    float inv = 1.0f / l;
    __bf16* ob = o + ((size_t)(b * Nq + (qb << 6) + (w << 4) + r)) * D_MODEL + hh * DHEAD;
#pragma unroll
    for (int dt = 0; dt < 4; ++dt) {
        bf16x4 ov;
#pragma unroll
        for (int rg = 0; rg < 4; ++rg) ov[rg] = (__bf16)(oacc[dt][rg] * inv);
        *(bf16x4*)&ob[(dt << 4) + (g << 2)] = ov;
    }
}

// ---------------------------------------------------------------------------
extern "C" void kernel_launch(void* const* d_in, const int* in_sizes, int n_in,
                              void* d_out, int out_size, void* d_ws, size_t ws_size,
                              hipStream_t stream) {
    const float* x    = (const float*)d_in[0];
    const float* t    = (const float*)d_in[1];
    const float* cond = (const float*)d_in[2];
    const float* n1_w = (const float*)d_in[3];
    const float* n1_b = (const float*)d_in[4];
    const float* n2_w = (const float*)d_in[5];
    const float* n2_b = (const float*)d_in[6];
    const float* n4_w = (const float*)d_in[7];
    const float* n4_b = (const float*)d_in[8];
    const float* a1_q = (const float*)d_in[9];
    const float* a1_k = (const float*)d_in[10];
    const float* a1_v = (const float*)d_in[11];
    const float* a1_o = (const float*)d_in[12];
    const float* a1_ob= (const float*)d_in[13];
    const float* a2_q = (const float*)d_in[14];
    const float* a2_k = (const float*)d_in[15];
    const float* a2_v = (const float*)d_in[16];
    const float* a2_o = (const float*)d_in[17];
    const float* a2_ob= (const float*)d_in[18];
    const float* ff_w1= (const float*)d_in[19];
    const float* ff_b1= (const float*)d_in[20];
    const float* ff_w2= (const float*)d_in[21];
    const float* ff_b2= (const float*)d_in[22];
    float* out = (float*)d_out;

    const int B  = in_sizes[1] / D_MODEL;              // 2
    const int N  = in_sizes[0] / (B * D_MODEL);        // 2048
    const int Nc = in_sizes[2] / (B * D_MODEL);        // 1024
    const int R  = B * N;                              // 4096
    const int Rc = B * Nc;                             // 2048

    // ---- workspace layout (~32.1 MB) -----------------------------------------
    char* Wb = (char*)d_ws;
    float* emb   = (float*)Wb;                                   // 32 KB
    __bf16* r1   = (__bf16*)(Wb + 32768);                        // 16 MB region
    __bf16* qkv  = r1;                                           // [R][1536]
    __bf16* q2   = r1;                                           // [R][512]
    __bf16* kv2  = r1 + (size_t)R * 512;                         // [Rc][1024]
    __bf16* gg   = r1;                                           // [R][2048]
    __bf16* h_bf = (__bf16*)(Wb + 32768 + 16777216);             // 4 MB
    __bf16* c_bf = (__bf16*)(Wb + 32768 + 16777216 + 4194304);   // 2 MB
    __bf16* wts  = (__bf16*)(Wb + 32768 + 16777216 + 4194304 + 2097152);
    __bf16* a1_qt = wts;                      // contiguous q,k,v -> fused QKV Bt
    __bf16* a1_ot = wts + 3 * 262144;
    __bf16* a2_qt = wts + 4 * 262144;
    __bf16* a2_kt = wts + 5 * 262144;         // contiguous k,v -> fused KV Bt
    __bf16* a2_ot = wts + 7 * 262144;
    __bf16* ff1t  = wts + 8 * 262144;         // [4096][512]
    __bf16* ff2t  = ff1t + 2097152;           // [512][2048]

    dim3 blk(256);

    // ---- prep -----------------------------------------------------------------
    adaln_params_kernel<<<dim3((3 * B * 2 * D_MODEL + 255) / 256), blk, 0, stream>>>(
        t, n1_w, n1_b, n2_w, n2_b, n4_w, n4_b, emb, B);

    WPtrs8 wp;
    wp.s[0] = a1_q; wp.s[1] = a1_k; wp.s[2] = a1_v; wp.s[3] = a1_o;
    wp.s[4] = a2_q; wp.s[5] = a2_k; wp.s[6] = a2_v; wp.s[7] = a2_o;
    wp.d[0] = a1_qt; wp.d[1] = wts + 262144; wp.d[2] = wts + 2 * 262144; wp.d[3] = a1_ot;
    wp.d[4] = a2_qt; wp.d[5] = a2_kt; wp.d[6] = wts + 6 * 262144; wp.d[7] = a2_ot;
    convt8_kernel<<<dim3(8, 8, 8), blk, 0, stream>>>(wp);
    convt_kernel<<<dim3(64, 8), blk, 0, stream>>>(ff_w1, ff1t, 512, 4096);
    convt_kernel<<<dim3(8, 32), blk, 0, stream>>>(ff_w2, ff2t, 2048, 512);
    convert_bf16v_kernel<<<dim3(Rc * D_MODEL / 1024), blk, 0, stream>>>(
        cond, c_bf, Rc * D_MODEL);

    // ---- block 1: self-attention -----------------------------------------------
    adaln_apply_kernel<<<dim3(R), blk, 0, stream>>>(x, emb, h_bf, N);
    gemm_bf16_kernel<2><<<dim3(24, R / 128), blk, 0, stream>>>(
        h_bf, a1_qt, nullptr, nullptr, qkv, R, 512, 1536);
    attn_mfma_kernel<<<dim3(B * NHEADS * (N / 64)), blk, 0, stream>>>(
        qkv, qkv + 512, qkv + 1024, h_bf, N, N, 1536, 1536);
    gemm_bf16_kernel<1><<<dim3(8, R / 128), blk, 0, stream>>>(
        h_bf, a1_ot, a1_ob, x, out, R, 512, 512);

    // ---- block 2: cross-attention ------------------------------------------------
    adaln_apply_kernel<<<dim3(R), blk, 0, stream>>>(
        out, emb + (size_t)B * 2 * D_MODEL, h_bf, N);
    gemm_bf16_kernel<0><<<dim3(16, Rc / 128), blk, 0, stream>>>(
        c_bf, a2_kt, nullptr, nullptr, kv2, Rc, 512, 1024);
    gemm_bf16_kernel<2><<<dim3(8, R / 128), blk, 0, stream>>>(
        h_bf, a2_qt, nullptr, nullptr, q2, R, 512, 512);
    attn_mfma_kernel<<<dim3(B * NHEADS * (N / 64)), blk, 0, stream>>>(
        q2, kv2, kv2 + 512, h_bf, N, Nc, 512, 1024);
    gemm_bf16_kernel<1><<<dim3(8, R / 128), blk, 0, stream>>>(
        h_bf, a2_ot, a2_ob, out, out, R, 512, 512);

    // ---- GEGLU feed-forward ---------------------------------------------------------
    adaln_apply_kernel<<<dim3(R), blk, 0, stream>>>(
        out, emb + (size_t)2 * B * 2 * D_MODEL, h_bf, N);
    gemm_geglu_bf16_kernel<<<dim3(32, R / 128), blk, 0, stream>>>(
        h_bf, ff1t, ff_b1, gg, R, 512);
    gemm_bf16_kernel<1><<<dim3(8, R / 128), blk, 0, stream>>>(
        gg, ff2t, ff_b2, out, out, R, 2048, 512);
}

// Round 5
// 229.451 us; speedup vs baseline: 17.3306x; 1.0959x over previous
//
#include <hip/hip_runtime.h>
#include <math.h>

#define D_MODEL 512
#define NHEADS  8
#define DHEAD   64

typedef __bf16  bf16x2 __attribute__((ext_vector_type(2)));
typedef __bf16  bf16x4 __attribute__((ext_vector_type(4)));
typedef __bf16  bf16x8 __attribute__((ext_vector_type(8)));
typedef float   f32x4  __attribute__((ext_vector_type(4)));

// global -> LDS direct copy, 16B per lane. LDS dest = wave-uniform base + lane*16.
__device__ __forceinline__ void gload16(const __bf16* g, __bf16* l) {
    __builtin_amdgcn_global_load_lds(
        (const __attribute__((address_space(1))) unsigned int*)g,
        (__attribute__((address_space(3))) unsigned int*)l, 16, 0, 0);
}

// ---------------------------------------------------------------------------
// Transpose+convert: src [K][N] fp32 -> dst [N][K] bf16.  64x64 LDS tile.
// ---------------------------------------------------------------------------
__device__ __forceinline__ void transpose_tile(
        const float* __restrict__ src, __bf16* __restrict__ dst,
        int K, int N, int k0, int n0) {
    __shared__ float t[64][65];
    int tid = threadIdx.x;
    int r = tid >> 6, c = tid & 63;
#pragma unroll
    for (int i = 0; i < 16; ++i)
        t[r + 4 * i][c] = src[(size_t)(k0 + r + 4 * i) * N + n0 + c];
    __syncthreads();
#pragma unroll
    for (int i = 0; i < 16; ++i)
        dst[(size_t)(n0 + r + 4 * i) * K + k0 + c] = (__bf16)t[c][r + 4 * i];
}

// ---------------------------------------------------------------------------
// Merged prep: adaln params GEMV + 10 weight transposes + cond fp32->bf16.
// ---------------------------------------------------------------------------
struct PrepArgs {
    const float *t, *n1w, *n1b, *n2w, *n2b, *n4w, *n4b;
    float* emb;
    const float* ws[8]; __bf16* wd[8];
    const float *ffw1, *ffw2;
    __bf16 *ff1t, *ff2t;
    const float* cond; __bf16* cbf;
    int B, condN;
};

__global__ __launch_bounds__(256) void prep_kernel(PrepArgs a) {
    int bb = blockIdx.x, tid = threadIdx.x;
    if (bb < 24) {
        int gI = bb * 256 + tid;
        int per = a.B * 2 * D_MODEL;
        if (gI >= 3 * per) return;
        int norm = gI / per;
        int rem  = gI - norm * per;
        int b = rem / (2 * D_MODEL);
        int c = rem % (2 * D_MODEL);
        const float* W  = (norm == 0) ? a.n1w : (norm == 1 ? a.n2w : a.n4w);
        const float* bb_= (norm == 0) ? a.n1b : (norm == 1 ? a.n2b : a.n4b);
        const float* trow = a.t + (size_t)b * D_MODEL;
        float acc = bb_[c];
        for (int k = 0; k < D_MODEL; ++k)
            acc = fmaf(trow[k], W[(size_t)k * (2 * D_MODEL) + c], acc);
        a.emb[gI] = acc;
    } else if (bb < 536) {
        int w = (bb - 24) >> 6, tI = (bb - 24) & 63;
        transpose_tile(a.ws[w], a.wd[w], 512, 512, (tI >> 3) << 6, (tI & 7) << 6);
    } else if (bb < 1048) {
        int tI = bb - 536;
        transpose_tile(a.ffw1, a.ff1t, 512, 4096, (tI & 7) << 6, (tI >> 3) << 6);
    } else if (bb < 1304) {
        int tI = bb - 1048;
        transpose_tile(a.ffw2, a.ff2t, 2048, 512, (tI >> 3) << 6, (tI & 7) << 6);
    } else {
        int i = ((bb - 1304) * 256 + tid) * 4;
        if (i >= a.condN) return;
        float4 v = *(const float4*)(a.cond + i);
        bf16x2 p0, p1;
        p0[0] = (__bf16)v.x; p0[1] = (__bf16)v.y;
        p1[0] = (__bf16)v.z; p1[1] = (__bf16)v.w;
        *(bf16x2*)(a.cbf + i)     = p0;
        *(bf16x2*)(a.cbf + i + 2) = p1;
    }
}

// ---------------------------------------------------------------------------
// AdaLN apply -> bf16 output. Block per row (512 cols, 2 per thread).
// ---------------------------------------------------------------------------
__global__ __launch_bounds__(256) void adaln_apply_kernel(
        const float* __restrict__ x, const float* __restrict__ emb_n,
        __bf16* __restrict__ h, int N) {
    int row = blockIdx.x;
    int b = row / N;
    const float* xr = x + (size_t)row * D_MODEL;
    int tid = threadIdx.x;
    float2 v = *(const float2*)(xr + 2 * tid);
    float s = v.x + v.y, sq = v.x * v.x + v.y * v.y;
#pragma unroll
    for (int off = 32; off; off >>= 1) {
        s  += __shfl_xor(s, off);
        sq += __shfl_xor(sq, off);
    }
    __shared__ float rs[4], rq[4];
    if ((tid & 63) == 0) { rs[tid >> 6] = s; rq[tid >> 6] = sq; }
    __syncthreads();
    float tot  = rs[0] + rs[1] + rs[2] + rs[3];
    float totq = rq[0] + rq[1] + rq[2] + rq[3];
    float mu  = tot * (1.0f / D_MODEL);
    float var = totq * (1.0f / D_MODEL) - mu * mu;
    float inv = rsqrtf(var + 1e-5f);
    const float* er = emb_n + (size_t)b * (2 * D_MODEL);
    float2 sc = *(const float2*)(er + 2 * tid);
    float2 sh = *(const float2*)(er + D_MODEL + 2 * tid);
    bf16x2 o;
    o[0] = (__bf16)((v.x - mu) * inv * (1.0f + sc.x) + sh.x);
    o[1] = (__bf16)((v.y - mu) * inv * (1.0f + sc.y) + sh.y);
    *(bf16x2*)(h + (size_t)row * D_MODEL + 2 * tid) = o;
}

// ---------------------------------------------------------------------------
// bf16 MFMA GEMM, m97 structure: global_load_lds staging, linear LDS with
// source-side column pre-swizzle + matching XOR on ds_read (slot ^= row&7).
// C = A[M,K] @ Bt[N,K]^T. Tile (2*WM)x64, BK=64, 4 waves (2x2).
// OUT=0: bf16. OUT=1: fp32 + bias + res. OUT=2: bf16, cols<512 scaled 0.125.
// ---------------------------------------------------------------------------
template<int OUT, int WM>
__global__ __launch_bounds__(256) void gemm_bf16_kernel(
        const __bf16* __restrict__ A, const __bf16* __restrict__ Bt,
        const float* __restrict__ bias, const float* __restrict__ res,
        void* __restrict__ Cv, int M, int K, int N) {
    constexpr int BM = 2 * WM;
    constexpr int MI = WM / 16;
    __shared__ __attribute__((aligned(16))) __bf16 As[BM * 64];
    __shared__ __attribute__((aligned(16))) __bf16 Bs[64 * 64];
    int tid = threadIdx.x;
    int wave = tid >> 6, lane = tid & 63;
    int wr = wave >> 1, wc = wave & 1;
    int r = lane & 15, g = lane >> 4;
    int rx = r & 7;
    int m0 = blockIdx.y * BM, n0 = blockIdx.x << 6;

    // staging: lane covers row (wave*8 + lane>>3), source col pre-swizzled
    int lrow = lane >> 3;
    int lcol = ((lane & 7) ^ lrow) << 3;
    const __bf16* Ag = A  + (size_t)(m0 + (wave << 3) + lrow) * K + lcol;
    const __bf16* Bg = Bt + (size_t)(n0 + (wave << 3) + lrow) * K + lcol;
    __bf16* AsW = As + (size_t)(wave << 3) * 64;
    __bf16* BsW = Bs + (size_t)(wave << 3) * 64;

    f32x4 acc[MI][2];
#pragma unroll
    for (int mi = 0; mi < MI; ++mi)
#pragma unroll
        for (int ni = 0; ni < 2; ++ni) acc[mi][ni] = (f32x4){0.f, 0.f, 0.f, 0.f};

    for (int k0 = 0; k0 < K; k0 += 64) {
        if (k0) __syncthreads();
#pragma unroll
        for (int i = 0; i < MI; ++i)
            gload16(Ag + (size_t)(i * 32) * K + k0, AsW + i * 32 * 64);
#pragma unroll
        for (int j = 0; j < 2; ++j)
            gload16(Bg + (size_t)(j * 32) * K + k0, BsW + j * 32 * 64);
        __syncthreads();   // compiler drains vmcnt before barrier
#pragma unroll
        for (int kk = 0; kk < 2; ++kk) {
            int cs = ((((kk << 2) + g) ^ rx) << 3);
            bf16x8 af[MI], bf_[2];
#pragma unroll
            for (int mi = 0; mi < MI; ++mi)
                af[mi] = *(const bf16x8*)&As[(size_t)(wr * WM + (mi << 4) + r) * 64 + cs];
#pragma unroll
            for (int ni = 0; ni < 2; ++ni)
                bf_[ni] = *(const bf16x8*)&Bs[(size_t)((wc << 5) + (ni << 4) + r) * 64 + cs];
#pragma unroll
            for (int mi = 0; mi < MI; ++mi)
#pragma unroll
                for (int ni = 0; ni < 2; ++ni)
                    acc[mi][ni] = __builtin_amdgcn_mfma_f32_16x16x32_bf16(
                        af[mi], bf_[ni], acc[mi][ni], 0, 0, 0);
        }
    }

#pragma unroll
    for (int mi = 0; mi < MI; ++mi) {
#pragma unroll
        for (int ni = 0; ni < 2; ++ni) {
            int col = n0 + (wc << 5) + (ni << 4) + r;
            float scl = (OUT == 2 && col < 512) ? 0.125f : 1.0f;
#pragma unroll
            for (int rg = 0; rg < 4; ++rg) {
                int row = m0 + wr * WM + (mi << 4) + (g << 2) + rg;
                if (OUT == 1) {
                    float v = acc[mi][ni][rg] + bias[col] + res[(size_t)row * N + col];
                    ((float*)Cv)[(size_t)row * N + col] = v;
                } else {
                    ((__bf16*)Cv)[(size_t)row * N + col] = (__bf16)(acc[mi][ni][rg] * scl);
                }
            }
        }
    }
}

// ---------------------------------------------------------------------------
// Fused GEGLU FF1 (bf16 MFMA, m97 staging): gg[M,2048] = u * gelu(g)
// ---------------------------------------------------------------------------
__global__ __launch_bounds__(256) void gemm_geglu_bf16_kernel(
        const __bf16* __restrict__ A, const __bf16* __restrict__ W1t,
        const float* __restrict__ b1, __bf16* __restrict__ gg, int M, int K) {
    const int NOUT = 4 * D_MODEL;   // 2048
    __shared__ __attribute__((aligned(16))) __bf16 AsL[128 * 64];
    __shared__ __attribute__((aligned(16))) __bf16 BuL[64 * 64];
    __shared__ __attribute__((aligned(16))) __bf16 BgL[64 * 64];
    int tid = threadIdx.x;
    int wave = tid >> 6, lane = tid & 63;
    int wr = wave >> 1, wc = wave & 1;
    int r = lane & 15, g = lane >> 4;
    int rx = r & 7;
    int m0 = blockIdx.y << 7, n0 = blockIdx.x << 6;

    int lrow = lane >> 3;
    int lcol = ((lane & 7) ^ lrow) << 3;
    const __bf16* Ag = A   + (size_t)(m0 + (wave << 3) + lrow) * K + lcol;
    const __bf16* Ug = W1t + (size_t)(n0 + (wave << 3) + lrow) * K + lcol;
    const __bf16* Gg = W1t + (size_t)(NOUT + n0 + (wave << 3) + lrow) * K + lcol;
    __bf16* AsW = AsL + (size_t)(wave << 3) * 64;
    __bf16* BuW = BuL + (size_t)(wave << 3) * 64;
    __bf16* BgW = BgL + (size_t)(wave << 3) * 64;

    f32x4 accu[4][2], accg[4][2];
#pragma unroll
    for (int mi = 0; mi < 4; ++mi)
#pragma unroll
        for (int ni = 0; ni < 2; ++ni) {
            accu[mi][ni] = (f32x4){0.f, 0.f, 0.f, 0.f};
            accg[mi][ni] = (f32x4){0.f, 0.f, 0.f, 0.f};
        }

    for (int k0 = 0; k0 < K; k0 += 64) {
        if (k0) __syncthreads();
#pragma unroll
        for (int i = 0; i < 4; ++i)
            gload16(Ag + (size_t)(i * 32) * K + k0, AsW + i * 32 * 64);
#pragma unroll
        for (int j = 0; j < 2; ++j) {
            gload16(Ug + (size_t)(j * 32) * K + k0, BuW + j * 32 * 64);
            gload16(Gg + (size_t)(j * 32) * K + k0, BgW + j * 32 * 64);
        }
        __syncthreads();
#pragma unroll
        for (int kk = 0; kk < 2; ++kk) {
            int cs = ((((kk << 2) + g) ^ rx) << 3);
            bf16x8 af[4], bu[2], bg[2];
#pragma unroll
            for (int mi = 0; mi < 4; ++mi)
                af[mi] = *(const bf16x8*)&AsL[(size_t)((wr << 6) + (mi << 4) + r) * 64 + cs];
#pragma unroll
            for (int ni = 0; ni < 2; ++ni) {
                bu[ni] = *(const bf16x8*)&BuL[(size_t)((wc << 5) + (ni << 4) + r) * 64 + cs];
                bg[ni] = *(const bf16x8*)&BgL[(size_t)((wc << 5) + (ni << 4) + r) * 64 + cs];
            }
#pragma unroll
            for (int mi = 0; mi < 4; ++mi)
#pragma unroll
                for (int ni = 0; ni < 2; ++ni) {
                    accu[mi][ni] = __builtin_amdgcn_mfma_f32_16x16x32_bf16(
                        af[mi], bu[ni], accu[mi][ni], 0, 0, 0);
                    accg[mi][ni] = __builtin_amdgcn_mfma_f32_16x16x32_bf16(
                        af[mi], bg[ni], accg[mi][ni], 0, 0, 0);
                }
        }
    }

#pragma unroll
    for (int mi = 0; mi < 4; ++mi) {
#pragma unroll
        for (int ni = 0; ni < 2; ++ni) {
            int col = n0 + (wc << 5) + (ni << 4) + r;
            float bu_ = b1[col], bg_ = b1[NOUT + col];
#pragma unroll
            for (int rg = 0; rg < 4; ++rg) {
                int row = m0 + (wr << 6) + (mi << 4) + (g << 2) + rg;
                float u  = accu[mi][ni][rg] + bu_;
                float gv = accg[mi][ni][rg] + bg_;
                float ge = 0.5f * gv * (1.0f + erff(gv * 0.70710678118654752f));
                gg[(size_t)row * NOUT + col] = (__bf16)(u * ge);
            }
        }
    }
}

// ---------------------------------------------------------------------------
// bf16 MFMA flash attention, swapped-operand form + defer-max + Pl nt-XOR.
// ---------------------------------------------------------------------------
__global__ __launch_bounds__(256) void attn_mfma_kernel(
        const __bf16* __restrict__ q, const __bf16* __restrict__ k,
        const __bf16* __restrict__ v, __bf16* __restrict__ o,
        int Nq, int Nk, int sq, int skv) {
    __shared__ __attribute__((aligned(16))) __bf16 Ks[64][72];
    __shared__ __attribute__((aligned(16))) __bf16 Vt[64 * 72];
    __shared__ __attribute__((aligned(16))) __bf16 Pl[4][16][72];

    int tid = threadIdx.x;
    int w = tid >> 6, lane = tid & 63;
    int r = lane & 15, g = lane >> 4;

    int nqb = Nq >> 6;
    int qb = blockIdx.x % nqb;
    int hh = (blockIdx.x / nqb) % NHEADS;
    int b  = blockIdx.x / (nqb * NHEADS);

    const __bf16* qp = q + ((size_t)(b * Nq + (qb << 6) + (w << 4) + r)) * sq
                         + hh * DHEAD + (g << 3);
    bf16x8 qf0 = *(const bf16x8*)qp;
    bf16x8 qf1 = *(const bf16x8*)(qp + 32);

    int krow = tid >> 2, kcb = (tid & 3) << 4;
    int va = tid & 31,  vbb = tid >> 5;
    size_t kvbase = (size_t)b * Nk * skv + (size_t)hh * DHEAD;
    const __bf16* kp = k + kvbase + (size_t)krow * skv + kcb;
    const __bf16* vp = v + kvbase + (size_t)(2 * va) * skv + (vbb << 3);

    f32x4 oacc[4];
#pragma unroll
    for (int dt = 0; dt < 4; ++dt) oacc[dt] = (f32x4){0.f, 0.f, 0.f, 0.f};
    float m = -1e30f, l = 0.f;

    bf16x8 kr0 = *(const bf16x8*)kp;
    bf16x8 kr1 = *(const bf16x8*)(kp + 8);
    bf16x8 vr0 = *(const bf16x8*)vp;
    bf16x8 vr1 = *(const bf16x8*)(vp + skv);
    {
        *(bf16x8*)&Ks[krow][kcb]     = kr0;
        *(bf16x8*)&Ks[krow][kcb + 8] = kr1;
        int blk = (va >> 2) ^ vbb;
        int cw  = ((va & 3) << 1);
#pragma unroll
        for (int j = 0; j < 8; ++j) {
            bf16x2 pr; pr[0] = vr0[j]; pr[1] = vr1[j];
            *(bf16x2*)&Vt[(size_t)(8 * vbb + j) * 72 + blk * 8 + cw] = pr;
        }
    }
    __syncthreads();

    int ntiles = Nk >> 6;
    for (int t = 0; t < ntiles; ++t) {
        bool pre = (t + 1 < ntiles);
        if (pre) {
            const __bf16* kp2 = kp + (size_t)(t + 1) * 64 * skv;
            const __bf16* vp2 = vp + (size_t)(t + 1) * 64 * skv;
            kr0 = *(const bf16x8*)kp2;
            kr1 = *(const bf16x8*)(kp2 + 8);
            vr0 = *(const bf16x8*)vp2;
            vr1 = *(const bf16x8*)(vp2 + skv);
        }

        // ---- S^T = K Q^T ------------------------------------------------------
        f32x4 sacc[4];
#pragma unroll
        for (int nt = 0; nt < 4; ++nt) sacc[nt] = (f32x4){0.f, 0.f, 0.f, 0.f};
        __builtin_amdgcn_s_setprio(1);
#pragma unroll
        for (int nt = 0; nt < 4; ++nt) {
            bf16x8 kf0 = *(const bf16x8*)&Ks[(nt << 4) + r][g << 3];
            bf16x8 kf1 = *(const bf16x8*)&Ks[(nt << 4) + r][32 + (g << 3)];
            sacc[nt] = __builtin_amdgcn_mfma_f32_16x16x32_bf16(kf0, qf0, sacc[nt], 0, 0, 0);
            sacc[nt] = __builtin_amdgcn_mfma_f32_16x16x32_bf16(kf1, qf1, sacc[nt], 0, 0, 0);
        }
        __builtin_amdgcn_s_setprio(0);

        // ---- online softmax, per-lane with defer-max ---------------------------
        float mx = sacc[0][0];
#pragma unroll
        for (int nt = 0; nt < 4; ++nt)
#pragma unroll
            for (int rg = 0; rg < 4; ++rg) mx = fmaxf(mx, sacc[nt][rg]);
        mx = fmaxf(mx, __shfl_xor(mx, 16));
        mx = fmaxf(mx, __shfl_xor(mx, 32));
        bool defer = __all(mx <= m + 8.0f);
        float mn = defer ? m : fmaxf(m, mx);
        if (!defer) {
            float al = __expf(m - mn);
            m = mn;
            l *= al;
#pragma unroll
            for (int dt = 0; dt < 4; ++dt)
#pragma unroll
                for (int rg = 0; rg < 4; ++rg) oacc[dt][rg] *= al;
        }
        float sum = 0.f;
#pragma unroll
        for (int nt = 0; nt < 4; ++nt) {
            bf16x4 pk;
#pragma unroll
            for (int rg = 0; rg < 4; ++rg) {
                float p = __expf(sacc[nt][rg] - mn);
                sum += p;
                pk[rg] = (__bf16)p;
            }
            *(bf16x4*)&Pl[w][r][((nt ^ (r & 3)) << 4) + (g << 2)] = pk;
        }
        sum += __shfl_xor(sum, 16);
        sum += __shfl_xor(sum, 32);
        l += sum;

        // ---- O^T += V^T P^T ----------------------------------------------------
        __builtin_amdgcn_s_setprio(1);
#pragma unroll
        for (int kh = 0; kh < 2; ++kh) {
            int bb_ = (kh << 1) + (g >> 1);
            bf16x8 pa = *(const bf16x8*)&Pl[w][r][((bb_ ^ (r & 3)) << 4) + ((g & 1) << 3)];
#pragma unroll
            for (int dt = 0; dt < 4; ++dt) {
                int row = (dt << 4) + r;
                int blk = ((kh << 2) + g) ^ ((row >> 3) & 7);
                bf16x8 vf = *(const bf16x8*)&Vt[(size_t)row * 72 + (blk << 3)];
                oacc[dt] = __builtin_amdgcn_mfma_f32_16x16x32_bf16(vf, pa, oacc[dt], 0, 0, 0);
            }
        }
        __builtin_amdgcn_s_setprio(0);

        __syncthreads();
        if (pre) {
            *(bf16x8*)&Ks[krow][kcb]     = kr0;
            *(bf16x8*)&Ks[krow][kcb + 8] = kr1;
            int blk = (va >> 2) ^ vbb;
            int cw  = ((va & 3) << 1);
#pragma unroll
            for (int j = 0; j < 8; ++j) {
                bf16x2 pr; pr[0] = vr0[j]; pr[1] = vr1[j];
                *(bf16x2*)&Vt[(size_t)(8 * vbb + j) * 72 + blk * 8 + cw] = pr;
            }
        }
        __syncthreads();
    }

    float inv = 1.0f / l;
    __bf16* ob = o + ((size_t)(b * Nq + (qb << 6) + (w << 4) + r)) * D_MODEL + hh * DHEAD;
#pragma unroll
    for (int dt = 0; dt < 4; ++dt) {
        bf16x4 ov;
#pragma unroll
        for (int rg = 0; rg < 4; ++rg) ov[rg] = (__bf16)(oacc[dt][rg] * inv);
        *(bf16x4*)&ob[(dt << 4) + (g << 2)] = ov;
    }
}

// ---------------------------------------------------------------------------
extern "C" void kernel_launch(void* const* d_in, const int* in_sizes, int n_in,
                              void* d_out, int out_size, void* d_ws, size_t ws_size,
                              hipStream_t stream) {
    const float* x    = (const float*)d_in[0];
    const float* t    = (const float*)d_in[1];
    const float* cond = (const float*)d_in[2];
    const float* n1_w = (const float*)d_in[3];
    const float* n1_b = (const float*)d_in[4];
    const float* n2_w = (const float*)d_in[5];
    const float* n2_b = (const float*)d_in[6];
    const float* n4_w = (const float*)d_in[7];
    const float* n4_b = (const float*)d_in[8];
    const float* a1_q = (const float*)d_in[9];
    const float* a1_k = (const float*)d_in[10];
    const float* a1_v = (const float*)d_in[11];
    const float* a1_o = (const float*)d_in[12];
    const float* a1_ob= (const float*)d_in[13];
    const float* a2_q = (const float*)d_in[14];
    const float* a2_k = (const float*)d_in[15];
    const float* a2_v = (const float*)d_in[16];
    const float* a2_o = (const float*)d_in[17];
    const float* a2_ob= (const float*)d_in[18];
    const float* ff_w1= (const float*)d_in[19];
    const float* ff_b1= (const float*)d_in[20];
    const float* ff_w2= (const float*)d_in[21];
    const float* ff_b2= (const float*)d_in[22];
    float* out = (float*)d_out;

    const int B  = in_sizes[1] / D_MODEL;              // 2
    const int N  = in_sizes[0] / (B * D_MODEL);        // 2048
    const int Nc = in_sizes[2] / (B * D_MODEL);        // 1024
    const int R  = B * N;                              // 4096
    const int Rc = B * Nc;                             // 2048

    // ---- workspace layout (~32.3 MB) -----------------------------------------
    char* Wb = (char*)d_ws;
    float* emb   = (float*)Wb;                                   // 32 KB
    __bf16* r1   = (__bf16*)(Wb + 32768);                        // 16 MB region
    __bf16* qkv  = r1;                                           // [R][1536]
    __bf16* q2   = r1;                                           // [R][512]
    __bf16* kv2  = r1 + (size_t)R * 512;                         // [Rc][1024]
    __bf16* gg   = r1;                                           // [R][2048]
    __bf16* h_bf = (__bf16*)(Wb + 32768 + 16777216);             // 4 MB
    __bf16* c_bf = (__bf16*)(Wb + 32768 + 16777216 + 4194304);   // 2 MB
    __bf16* wts  = (__bf16*)(Wb + 32768 + 16777216 + 4194304 + 2097152);
    __bf16* a1_qt = wts;                      // contiguous q,k,v -> fused QKV Bt
    __bf16* a1_ot = wts + 3 * 262144;
    __bf16* a2_qt = wts + 4 * 262144;
    __bf16* a2_kt = wts + 5 * 262144;         // contiguous k,v -> fused KV Bt
    __bf16* a2_ot = wts + 7 * 262144;
    __bf16* ff1t  = wts + 8 * 262144;         // [4096][512]
    __bf16* ff2t  = ff1t + 2097152;           // [512][2048]

    dim3 blk(256);

    // ---- single merged prep dispatch -------------------------------------------
    PrepArgs pa;
    pa.t = t; pa.n1w = n1_w; pa.n1b = n1_b; pa.n2w = n2_w; pa.n2b = n2_b;
    pa.n4w = n4_w; pa.n4b = n4_b; pa.emb = emb;
    pa.ws[0] = a1_q; pa.ws[1] = a1_k; pa.ws[2] = a1_v; pa.ws[3] = a1_o;
    pa.ws[4] = a2_q; pa.ws[5] = a2_k; pa.ws[6] = a2_v; pa.ws[7] = a2_o;
    pa.wd[0] = a1_qt; pa.wd[1] = wts + 262144; pa.wd[2] = wts + 2 * 262144; pa.wd[3] = a1_ot;
    pa.wd[4] = a2_qt; pa.wd[5] = a2_kt; pa.wd[6] = wts + 6 * 262144; pa.wd[7] = a2_ot;
    pa.ffw1 = ff_w1; pa.ffw2 = ff_w2; pa.ff1t = ff1t; pa.ff2t = ff2t;
    pa.cond = cond; pa.cbf = c_bf; pa.B = B; pa.condN = Rc * D_MODEL;
    prep_kernel<<<dim3(1304 + (Rc * D_MODEL) / 1024), blk, 0, stream>>>(pa);

    // ---- block 1: self-attention -----------------------------------------------
    adaln_apply_kernel<<<dim3(R), blk, 0, stream>>>(x, emb, h_bf, N);
    gemm_bf16_kernel<2, 64><<<dim3(24, R / 128), blk, 0, stream>>>(
        h_bf, a1_qt, nullptr, nullptr, qkv, R, 512, 1536);
    attn_mfma_kernel<<<dim3(B * NHEADS * (N / 64)), blk, 0, stream>>>(
        qkv, qkv + 512, qkv + 1024, h_bf, N, N, 1536, 1536);
    gemm_bf16_kernel<1, 32><<<dim3(8, R / 64), blk, 0, stream>>>(
        h_bf, a1_ot, a1_ob, x, out, R, 512, 512);

    // ---- block 2: cross-attention ------------------------------------------------
    adaln_apply_kernel<<<dim3(R), blk, 0, stream>>>(
        out, emb + (size_t)B * 2 * D_MODEL, h_bf, N);
    gemm_bf16_kernel<0, 32><<<dim3(16, Rc / 64), blk, 0, stream>>>(
        c_bf, a2_kt, nullptr, nullptr, kv2, Rc, 512, 1024);
    gemm_bf16_kernel<2, 32><<<dim3(8, R / 64), blk, 0, stream>>>(
        h_bf, a2_qt, nullptr, nullptr, q2, R, 512, 512);
    attn_mfma_kernel<<<dim3(B * NHEADS * (N / 64)), blk, 0, stream>>>(
        q2, kv2, kv2 + 512, h_bf, N, Nc, 512, 1024);
    gemm_bf16_kernel<1, 32><<<dim3(8, R / 64), blk, 0, stream>>>(
        h_bf, a2_ot, a2_ob, out, out, R, 512, 512);

    // ---- GEGLU feed-forward ---------------------------------------------------------
    adaln_apply_kernel<<<dim3(R), blk, 0, stream>>>(
        out, emb + (size_t)2 * B * 2 * D_MODEL, h_bf, N);
    gemm_geglu_bf16_kernel<<<dim3(32, R / 128), blk, 0, stream>>>(
        h_bf, ff1t, ff_b1, gg, R, 512);
    gemm_bf16_kernel<1, 32><<<dim3(8, R / 64), blk, 0, stream>>>(
        gg, ff2t, ff_b2, out, out, R, 2048, 512);
}

// Round 6
// 218.362 us; speedup vs baseline: 18.2106x; 1.0508x over previous
//
#include <hip/hip_runtime.h>
#include <math.h>

#define D_MODEL 512
#define NHEADS  8
#define DHEAD   64

typedef __bf16  bf16x2 __attribute__((ext_vector_type(2)));
typedef __bf16  bf16x4 __attribute__((ext_vector_type(4)));
typedef __bf16  bf16x8 __attribute__((ext_vector_type(8)));
typedef float   f32x4  __attribute__((ext_vector_type(4)));

#define QSCALE 0.18033688f   /* 0.125 * log2(e): softmax runs in exp2 domain */
#define DEFER_THR 11.5416f   /* 8 nats in log2 units */

// global -> LDS direct copy, 16B per lane. LDS dest = wave-uniform base + lane*16.
__device__ __forceinline__ void gload16(const __bf16* g, __bf16* l) {
    __builtin_amdgcn_global_load_lds(
        (const __attribute__((address_space(1))) unsigned int*)g,
        (__attribute__((address_space(3))) unsigned int*)l, 16, 0, 0);
}

// ---------------------------------------------------------------------------
// Transpose+convert: src [K][N] fp32 -> dst [N][K] bf16.  64x64 LDS tile.
// ---------------------------------------------------------------------------
__device__ __forceinline__ void transpose_tile(
        const float* __restrict__ src, __bf16* __restrict__ dst,
        int K, int N, int k0, int n0) {
    __shared__ float t[64][65];
    int tid = threadIdx.x;
    int r = tid >> 6, c = tid & 63;
#pragma unroll
    for (int i = 0; i < 16; ++i)
        t[r + 4 * i][c] = src[(size_t)(k0 + r + 4 * i) * N + n0 + c];
    __syncthreads();
#pragma unroll
    for (int i = 0; i < 16; ++i)
        dst[(size_t)(n0 + r + 4 * i) * K + k0 + c] = (__bf16)t[c][r + 4 * i];
}

// ---------------------------------------------------------------------------
// Merged prep: adaln params GEMV + 10 weight transposes + cond fp32->bf16.
// ---------------------------------------------------------------------------
struct PrepArgs {
    const float *t, *n1w, *n1b, *n2w, *n2b, *n4w, *n4b;
    float* emb;
    const float* ws[8]; __bf16* wd[8];
    const float *ffw1, *ffw2;
    __bf16 *ff1t, *ff2t;
    const float* cond; __bf16* cbf;
    int B, condN;
};

__global__ __launch_bounds__(256) void prep_kernel(PrepArgs a) {
    int bb = blockIdx.x, tid = threadIdx.x;
    if (bb < 24) {
        int gI = bb * 256 + tid;
        int per = a.B * 2 * D_MODEL;
        if (gI >= 3 * per) return;
        int norm = gI / per;
        int rem  = gI - norm * per;
        int b = rem / (2 * D_MODEL);
        int c = rem % (2 * D_MODEL);
        const float* W  = (norm == 0) ? a.n1w : (norm == 1 ? a.n2w : a.n4w);
        const float* bb_= (norm == 0) ? a.n1b : (norm == 1 ? a.n2b : a.n4b);
        const float* trow = a.t + (size_t)b * D_MODEL;
        float acc = bb_[c];
        for (int k = 0; k < D_MODEL; ++k)
            acc = fmaf(trow[k], W[(size_t)k * (2 * D_MODEL) + c], acc);
        a.emb[gI] = acc;
    } else if (bb < 536) {
        int w = (bb - 24) >> 6, tI = (bb - 24) & 63;
        transpose_tile(a.ws[w], a.wd[w], 512, 512, (tI >> 3) << 6, (tI & 7) << 6);
    } else if (bb < 1048) {
        int tI = bb - 536;
        transpose_tile(a.ffw1, a.ff1t, 512, 4096, (tI & 7) << 6, (tI >> 3) << 6);
    } else if (bb < 1304) {
        int tI = bb - 1048;
        transpose_tile(a.ffw2, a.ff2t, 2048, 512, (tI >> 3) << 6, (tI & 7) << 6);
    } else {
        int i = ((bb - 1304) * 256 + tid) * 4;
        if (i >= a.condN) return;
        float4 v = *(const float4*)(a.cond + i);
        bf16x2 p0, p1;
        p0[0] = (__bf16)v.x; p0[1] = (__bf16)v.y;
        p1[0] = (__bf16)v.z; p1[1] = (__bf16)v.w;
        *(bf16x2*)(a.cbf + i)     = p0;
        *(bf16x2*)(a.cbf + i + 2) = p1;
    }
}

// ---------------------------------------------------------------------------
// AdaLN apply -> bf16 output. Block per row (512 cols, 2 per thread).
// ---------------------------------------------------------------------------
__global__ __launch_bounds__(256) void adaln_apply_kernel(
        const float* __restrict__ x, const float* __restrict__ emb_n,
        __bf16* __restrict__ h, int N) {
    int row = blockIdx.x;
    int b = row / N;
    const float* xr = x + (size_t)row * D_MODEL;
    int tid = threadIdx.x;
    float2 v = *(const float2*)(xr + 2 * tid);
    float s = v.x + v.y, sq = v.x * v.x + v.y * v.y;
#pragma unroll
    for (int off = 32; off; off >>= 1) {
        s  += __shfl_xor(s, off);
        sq += __shfl_xor(sq, off);
    }
    __shared__ float rs[4], rq[4];
    if ((tid & 63) == 0) { rs[tid >> 6] = s; rq[tid >> 6] = sq; }
    __syncthreads();
    float tot  = rs[0] + rs[1] + rs[2] + rs[3];
    float totq = rq[0] + rq[1] + rq[2] + rq[3];
    float mu  = tot * (1.0f / D_MODEL);
    float var = totq * (1.0f / D_MODEL) - mu * mu;
    float inv = rsqrtf(var + 1e-5f);
    const float* er = emb_n + (size_t)b * (2 * D_MODEL);
    float2 sc = *(const float2*)(er + 2 * tid);
    float2 sh = *(const float2*)(er + D_MODEL + 2 * tid);
    bf16x2 o;
    o[0] = (__bf16)((v.x - mu) * inv * (1.0f + sc.x) + sh.x);
    o[1] = (__bf16)((v.y - mu) * inv * (1.0f + sc.y) + sh.y);
    *(bf16x2*)(h + (size_t)row * D_MODEL + 2 * tid) = o;
}

// ---------------------------------------------------------------------------
// bf16 MFMA GEMM body (m97 structure). C = A[M,K] @ Bt[N,K]^T.
// OUT=0: bf16. OUT=1: fp32 + bias + res. OUT=2: bf16, cols<512 scaled QSCALE.
// ---------------------------------------------------------------------------
template<int OUT, int WM>
__device__ __forceinline__ void gemm_body(
        const __bf16* __restrict__ A, const __bf16* __restrict__ Bt,
        const float* __restrict__ bias, const float* __restrict__ res,
        void* __restrict__ Cv, int M, int K, int N, int bx, int by,
        __bf16* As, __bf16* Bs) {
    constexpr int MI = WM / 16;
    int tid = threadIdx.x;
    int wave = tid >> 6, lane = tid & 63;
    int wr = wave >> 1, wc = wave & 1;
    int r = lane & 15, g = lane >> 4;
    int rx = r & 7;
    int m0 = by * (2 * WM), n0 = bx << 6;

    int lrow = lane >> 3;
    int lcol = ((lane & 7) ^ lrow) << 3;
    const __bf16* Ag = A  + (size_t)(m0 + (wave << 3) + lrow) * K + lcol;
    const __bf16* Bg = Bt + (size_t)(n0 + (wave << 3) + lrow) * K + lcol;
    __bf16* AsW = As + (size_t)(wave << 3) * 64;
    __bf16* BsW = Bs + (size_t)(wave << 3) * 64;

    f32x4 acc[MI][2];
#pragma unroll
    for (int mi = 0; mi < MI; ++mi)
#pragma unroll
        for (int ni = 0; ni < 2; ++ni) acc[mi][ni] = (f32x4){0.f, 0.f, 0.f, 0.f};

    for (int k0 = 0; k0 < K; k0 += 64) {
        if (k0) __syncthreads();
#pragma unroll
        for (int i = 0; i < MI; ++i)
            gload16(Ag + (size_t)(i * 32) * K + k0, AsW + i * 32 * 64);
#pragma unroll
        for (int j = 0; j < 2; ++j)
            gload16(Bg + (size_t)(j * 32) * K + k0, BsW + j * 32 * 64);
        __syncthreads();
#pragma unroll
        for (int kk = 0; kk < 2; ++kk) {
            int cs = ((((kk << 2) + g) ^ rx) << 3);
            bf16x8 af[MI], bf_[2];
#pragma unroll
            for (int mi = 0; mi < MI; ++mi)
                af[mi] = *(const bf16x8*)&As[(size_t)(wr * WM + (mi << 4) + r) * 64 + cs];
#pragma unroll
            for (int ni = 0; ni < 2; ++ni)
                bf_[ni] = *(const bf16x8*)&Bs[(size_t)((wc << 5) + (ni << 4) + r) * 64 + cs];
#pragma unroll
            for (int mi = 0; mi < MI; ++mi)
#pragma unroll
                for (int ni = 0; ni < 2; ++ni)
                    acc[mi][ni] = __builtin_amdgcn_mfma_f32_16x16x32_bf16(
                        af[mi], bf_[ni], acc[mi][ni], 0, 0, 0);
        }
    }

#pragma unroll
    for (int mi = 0; mi < MI; ++mi) {
#pragma unroll
        for (int ni = 0; ni < 2; ++ni) {
            int col = n0 + (wc << 5) + (ni << 4) + r;
            float scl = (OUT == 2 && col < 512) ? QSCALE : 1.0f;
#pragma unroll
            for (int rg = 0; rg < 4; ++rg) {
                int row = m0 + wr * WM + (mi << 4) + (g << 2) + rg;
                if (OUT == 1) {
                    float v = acc[mi][ni][rg] + bias[col] + res[(size_t)row * N + col];
                    ((float*)Cv)[(size_t)row * N + col] = v;
                } else {
                    ((__bf16*)Cv)[(size_t)row * N + col] = (__bf16)(acc[mi][ni][rg] * scl);
                }
            }
        }
    }
}

template<int OUT, int WM>
__global__ __launch_bounds__(256) void gemm_bf16_kernel(
        const __bf16* __restrict__ A, const __bf16* __restrict__ Bt,
        const float* __restrict__ bias, const float* __restrict__ res,
        void* __restrict__ Cv, int M, int K, int N) {
    __shared__ __attribute__((aligned(16))) __bf16 As[2 * WM * 64];
    __shared__ __attribute__((aligned(16))) __bf16 Bs[64 * 64];
    gemm_body<OUT, WM>(A, Bt, bias, res, Cv, M, K, N, blockIdx.x, blockIdx.y, As, Bs);
}

// q2 (OUT=2) and kv2 (OUT=0) fused in one dispatch.
__global__ __launch_bounds__(256) void gemm_dual_kernel(
        const __bf16* A0, const __bf16* B0, __bf16* C0, int M0,
        const __bf16* A1, const __bf16* B1, __bf16* C1, int M1) {
    __shared__ __attribute__((aligned(16))) __bf16 As[64 * 64];
    __shared__ __attribute__((aligned(16))) __bf16 Bs[64 * 64];
    int nb0 = 8 * (M0 >> 6);
    if ((int)blockIdx.x < nb0) {
        gemm_body<2, 32>(A0, B0, nullptr, nullptr, C0, M0, 512, 512,
                         blockIdx.x & 7, blockIdx.x >> 3, As, Bs);
    } else {
        int id = blockIdx.x - nb0;
        gemm_body<0, 32>(A1, B1, nullptr, nullptr, C1, M1, 512, 1024,
                         id & 15, id >> 4, As, Bs);
    }
}

// ---------------------------------------------------------------------------
// Fused GEGLU FF1 (bf16 MFMA, m97 staging): gg[M,2048] = u * gelu(g)
// ---------------------------------------------------------------------------
__global__ __launch_bounds__(256) void gemm_geglu_bf16_kernel(
        const __bf16* __restrict__ A, const __bf16* __restrict__ W1t,
        const float* __restrict__ b1, __bf16* __restrict__ gg, int M, int K) {
    const int NOUT = 4 * D_MODEL;   // 2048
    __shared__ __attribute__((aligned(16))) __bf16 AsL[128 * 64];
    __shared__ __attribute__((aligned(16))) __bf16 BuL[64 * 64];
    __shared__ __attribute__((aligned(16))) __bf16 BgL[64 * 64];
    int tid = threadIdx.x;
    int wave = tid >> 6, lane = tid & 63;
    int wr = wave >> 1, wc = wave & 1;
    int r = lane & 15, g = lane >> 4;
    int rx = r & 7;
    int m0 = blockIdx.y << 7, n0 = blockIdx.x << 6;

    int lrow = lane >> 3;
    int lcol = ((lane & 7) ^ lrow) << 3;
    const __bf16* Ag = A   + (size_t)(m0 + (wave << 3) + lrow) * K + lcol;
    const __bf16* Ug = W1t + (size_t)(n0 + (wave << 3) + lrow) * K + lcol;
    const __bf16* Gg = W1t + (size_t)(NOUT + n0 + (wave << 3) + lrow) * K + lcol;
    __bf16* AsW = AsL + (size_t)(wave << 3) * 64;
    __bf16* BuW = BuL + (size_t)(wave << 3) * 64;
    __bf16* BgW = BgL + (size_t)(wave << 3) * 64;

    f32x4 accu[4][2], accg[4][2];
#pragma unroll
    for (int mi = 0; mi < 4; ++mi)
#pragma unroll
        for (int ni = 0; ni < 2; ++ni) {
            accu[mi][ni] = (f32x4){0.f, 0.f, 0.f, 0.f};
            accg[mi][ni] = (f32x4){0.f, 0.f, 0.f, 0.f};
        }

    for (int k0 = 0; k0 < K; k0 += 64) {
        if (k0) __syncthreads();
#pragma unroll
        for (int i = 0; i < 4; ++i)
            gload16(Ag + (size_t)(i * 32) * K + k0, AsW + i * 32 * 64);
#pragma unroll
        for (int j = 0; j < 2; ++j) {
            gload16(Ug + (size_t)(j * 32) * K + k0, BuW + j * 32 * 64);
            gload16(Gg + (size_t)(j * 32) * K + k0, BgW + j * 32 * 64);
        }
        __syncthreads();
#pragma unroll
        for (int kk = 0; kk < 2; ++kk) {
            int cs = ((((kk << 2) + g) ^ rx) << 3);
            bf16x8 af[4], bu[2], bg[2];
#pragma unroll
            for (int mi = 0; mi < 4; ++mi)
                af[mi] = *(const bf16x8*)&AsL[(size_t)((wr << 6) + (mi << 4) + r) * 64 + cs];
#pragma unroll
            for (int ni = 0; ni < 2; ++ni) {
                bu[ni] = *(const bf16x8*)&BuL[(size_t)((wc << 5) + (ni << 4) + r) * 64 + cs];
                bg[ni] = *(const bf16x8*)&BgL[(size_t)((wc << 5) + (ni << 4) + r) * 64 + cs];
            }
#pragma unroll
            for (int mi = 0; mi < 4; ++mi)
#pragma unroll
                for (int ni = 0; ni < 2; ++ni) {
                    accu[mi][ni] = __builtin_amdgcn_mfma_f32_16x16x32_bf16(
                        af[mi], bu[ni], accu[mi][ni], 0, 0, 0);
                    accg[mi][ni] = __builtin_amdgcn_mfma_f32_16x16x32_bf16(
                        af[mi], bg[ni], accg[mi][ni], 0, 0, 0);
                }
        }
    }

#pragma unroll
    for (int mi = 0; mi < 4; ++mi) {
#pragma unroll
        for (int ni = 0; ni < 2; ++ni) {
            int col = n0 + (wc << 5) + (ni << 4) + r;
            float bu_ = b1[col], bg_ = b1[NOUT + col];
#pragma unroll
            for (int rg = 0; rg < 4; ++rg) {
                int row = m0 + (wr << 6) + (mi << 4) + (g << 2) + rg;
                float u  = accu[mi][ni][rg] + bu_;
                float gv = accg[mi][ni][rg] + bg_;
                float ge = 0.5f * gv * (1.0f + erff(gv * 0.70710678118654752f));
                gg[(size_t)row * NOUT + col] = (__bf16)(u * ge);
            }
        }
    }
}

// ---------------------------------------------------------------------------
// bf16 MFMA flash attention v2: swapped operands, exp2-domain softmax,
// double-buffered K/V (1 barrier/tile), uniform XOR-16B swizzle (m214 recipe),
// cross-tile QK^T/softmax overlap via sacc ping-pong.
// Q must be pre-scaled by 0.125*log2(e) (folded into projection).
// ---------------------------------------------------------------------------
__global__ __launch_bounds__(256) void attn_mfma_kernel(
        const __bf16* __restrict__ q, const __bf16* __restrict__ k,
        const __bf16* __restrict__ v, __bf16* __restrict__ o,
        int Nq, int Nk, int sq, int skv) {
    __shared__ __attribute__((aligned(16))) __bf16 Ks[2][4096];  // [key][64d], 128B rows
    __shared__ __attribute__((aligned(16))) __bf16 Vt[2][4096];  // [dim][64key]
    __shared__ __attribute__((aligned(16))) __bf16 Pl[4][1024];  // per-wave [qrow][64key]

    int tid = threadIdx.x;
    int w = tid >> 6, lane = tid & 63;
    int r = lane & 15, g = lane >> 4;
    int rx = r & 7;

    int nqb = Nq >> 6;
    int qb = blockIdx.x % nqb;
    int hh = (blockIdx.x / nqb) % NHEADS;
    int b  = blockIdx.x / (nqb * NHEADS);

    const __bf16* qp = q + ((size_t)(b * Nq + (qb << 6) + (w << 4) + r)) * sq
                         + hh * DHEAD + (g << 3);
    bf16x8 qf0 = *(const bf16x8*)qp;
    bf16x8 qf1 = *(const bf16x8*)(qp + 32);

    // staging maps
    int krow = tid >> 2, kp_ = tid & 3;
    int va = tid & 31, vbb = tid >> 5;
    size_t kvbase = (size_t)b * Nk * skv + (size_t)hh * DHEAD;
    const __bf16* kp = k + kvbase + (size_t)krow * skv + (kp_ << 4);
    const __bf16* vp = v + kvbase + (size_t)(2 * va) * skv + (vbb << 3);
    int kwo0 = krow * 64 + ((((kp_ << 1) | 0) ^ (krow & 7)) << 3);
    int kwo1 = krow * 64 + ((((kp_ << 1) | 1) ^ (krow & 7)) << 3);
    int vwb  = vbb * 512 + ((va & 3) << 1);   // + j*64 + (((va>>2)^j)<<3)

    f32x4 oacc[4];
#pragma unroll
    for (int dt = 0; dt < 4; ++dt) oacc[dt] = (f32x4){0.f, 0.f, 0.f, 0.f};
    float m = -1e30f, l = 0.f;
    f32x4 saccA[4], saccB[4];
    bf16x8 kr0, kr1, vr0, vr1;
    bf16x8 vf[2][4], pa[2];

    auto LOADREG = [&](int t) {
        const __bf16* kp2 = kp + (size_t)t * 64 * skv;
        const __bf16* vp2 = vp + (size_t)t * 64 * skv;
        kr0 = *(const bf16x8*)kp2; kr1 = *(const bf16x8*)(kp2 + 8);
        vr0 = *(const bf16x8*)vp2; vr1 = *(const bf16x8*)(vp2 + skv);
    };
    auto STAGEW = [&](int buf) {
        *(bf16x8*)&Ks[buf][kwo0] = kr0;
        *(bf16x8*)&Ks[buf][kwo1] = kr1;
#pragma unroll
        for (int j = 0; j < 8; ++j) {
            bf16x2 pr; pr[0] = vr0[j]; pr[1] = vr1[j];
            *(bf16x2*)&Vt[buf][vwb + j * 64 + (((va >> 2) ^ j) << 3)] = pr;
        }
    };
    auto QKT = [&](f32x4 (&sacc)[4], int buf) {
#pragma unroll
        for (int nt = 0; nt < 4; ++nt) sacc[nt] = (f32x4){0.f, 0.f, 0.f, 0.f};
        __builtin_amdgcn_s_setprio(1);
#pragma unroll
        for (int nt = 0; nt < 4; ++nt) {
            bf16x8 kf0 = *(const bf16x8*)&Ks[buf][((nt << 4) + r) * 64 + ((g ^ rx) << 3)];
            bf16x8 kf1 = *(const bf16x8*)&Ks[buf][((nt << 4) + r) * 64 + (((g + 4) ^ rx) << 3)];
            sacc[nt] = __builtin_amdgcn_mfma_f32_16x16x32_bf16(kf0, qf0, sacc[nt], 0, 0, 0);
            sacc[nt] = __builtin_amdgcn_mfma_f32_16x16x32_bf16(kf1, qf1, sacc[nt], 0, 0, 0);
        }
        __builtin_amdgcn_s_setprio(0);
    };
    auto SMAX = [&](f32x4 (&sacc)[4]) {
        float mx = sacc[0][0];
#pragma unroll
        for (int nt = 0; nt < 4; ++nt)
#pragma unroll
            for (int rg = 0; rg < 4; ++rg) mx = fmaxf(mx, sacc[nt][rg]);
        mx = fmaxf(mx, __shfl_xor(mx, 16));
        mx = fmaxf(mx, __shfl_xor(mx, 32));
        if (!__all(mx <= m + DEFER_THR)) {
            float mn = fmaxf(m, mx);
            float al = exp2f(m - mn);
            m = mn; l *= al;
#pragma unroll
            for (int dt = 0; dt < 4; ++dt)
#pragma unroll
                for (int rg = 0; rg < 4; ++rg) oacc[dt][rg] *= al;
        }
        float sum = 0.f;
#pragma unroll
        for (int nt = 0; nt < 4; ++nt) {
            bf16x4 pk;
#pragma unroll
            for (int rg = 0; rg < 4; ++rg) {
                float p = exp2f(sacc[nt][rg] - m);
                sum += p;
                pk[rg] = (__bf16)p;
            }
            *(bf16x4*)&Pl[w][r * 64 + ((((nt << 1) | (g >> 1)) ^ rx) << 3) + ((g & 1) << 2)] = pk;
        }
        sum += __shfl_xor(sum, 16);
        sum += __shfl_xor(sum, 32);
        l += sum;
    };
    auto VFLOAD = [&](int buf) {
#pragma unroll
        for (int kh = 0; kh < 2; ++kh) {
            pa[kh] = *(const bf16x8*)&Pl[w][r * 64 + ((((kh << 2) + g) ^ rx) << 3)];
#pragma unroll
            for (int dt = 0; dt < 4; ++dt)
                vf[kh][dt] = *(const bf16x8*)&Vt[buf][((dt << 4) + r) * 64
                                                      + ((((kh << 2) + g) ^ rx) << 3)];
        }
    };
    auto PVOP = [&]() {
        __builtin_amdgcn_s_setprio(1);
#pragma unroll
        for (int kh = 0; kh < 2; ++kh)
#pragma unroll
            for (int dt = 0; dt < 4; ++dt)
                oacc[dt] = __builtin_amdgcn_mfma_f32_16x16x32_bf16(
                    vf[kh][dt], pa[kh], oacc[dt], 0, 0, 0);
        __builtin_amdgcn_s_setprio(0);
    };

    int ntiles = Nk >> 6;   // always even (>=2) for our shapes
    // ---- prologue ----------------------------------------------------------
    LOADREG(0);
    STAGEW(0);
    LOADREG(1);
    __syncthreads();
    QKT(saccA, 0);

    for (int t = 0; t + 1 < ntiles; t += 2) {
        // ---- even phase: tile t (buf0, saccA); regs hold t+1 ----------------
        STAGEW(1);
        if (t + 2 < ntiles) LOADREG(t + 2);
        SMAX(saccA);
        VFLOAD(0);
        __syncthreads();
        QKT(saccB, 1);
        PVOP();
        // ---- odd phase: tile t+1 (buf1, saccB); regs hold t+2 ---------------
        if (t + 2 < ntiles) {
            STAGEW(0);
            if (t + 3 < ntiles) LOADREG(t + 3);
        }
        SMAX(saccB);
        VFLOAD(1);
        __syncthreads();
        if (t + 2 < ntiles) QKT(saccA, 0);
        PVOP();
    }

    // ---- epilogue: O^T/l -> o[qrow][dim] ------------------------------------
    float inv = 1.0f / l;
    __bf16* ob = o + ((size_t)(b * Nq + (qb << 6) + (w << 4) + r)) * D_MODEL + hh * DHEAD;
#pragma unroll
    for (int dt = 0; dt < 4; ++dt) {
        bf16x4 ov;
#pragma unroll
        for (int rg = 0; rg < 4; ++rg) ov[rg] = (__bf16)(oacc[dt][rg] * inv);
        *(bf16x4*)&ob[(dt << 4) + (g << 2)] = ov;
    }
}

// ---------------------------------------------------------------------------
extern "C" void kernel_launch(void* const* d_in, const int* in_sizes, int n_in,
                              void* d_out, int out_size, void* d_ws, size_t ws_size,
                              hipStream_t stream) {
    const float* x    = (const float*)d_in[0];
    const float* t    = (const float*)d_in[1];
    const float* cond = (const float*)d_in[2];
    const float* n1_w = (const float*)d_in[3];
    const float* n1_b = (const float*)d_in[4];
    const float* n2_w = (const float*)d_in[5];
    const float* n2_b = (const float*)d_in[6];
    const float* n4_w = (const float*)d_in[7];
    const float* n4_b = (const float*)d_in[8];
    const float* a1_q = (const float*)d_in[9];
    const float* a1_k = (const float*)d_in[10];
    const float* a1_v = (const float*)d_in[11];
    const float* a1_o = (const float*)d_in[12];
    const float* a1_ob= (const float*)d_in[13];
    const float* a2_q = (const float*)d_in[14];
    const float* a2_k = (const float*)d_in[15];
    const float* a2_v = (const float*)d_in[16];
    const float* a2_o = (const float*)d_in[17];
    const float* a2_ob= (const float*)d_in[18];
    const float* ff_w1= (const float*)d_in[19];
    const float* ff_b1= (const float*)d_in[20];
    const float* ff_w2= (const float*)d_in[21];
    const float* ff_b2= (const float*)d_in[22];
    float* out = (float*)d_out;

    const int B  = in_sizes[1] / D_MODEL;              // 2
    const int N  = in_sizes[0] / (B * D_MODEL);        // 2048
    const int Nc = in_sizes[2] / (B * D_MODEL);        // 1024
    const int R  = B * N;                              // 4096
    const int Rc = B * Nc;                             // 2048

    // ---- workspace layout (~32.3 MB) -----------------------------------------
    char* Wb = (char*)d_ws;
    float* emb   = (float*)Wb;                                   // 32 KB
    __bf16* r1   = (__bf16*)(Wb + 32768);                        // 16 MB region
    __bf16* qkv  = r1;                                           // [R][1536]
    __bf16* q2   = r1;                                           // [R][512]
    __bf16* kv2  = r1 + (size_t)R * 512;                         // [Rc][1024]
    __bf16* gg   = r1;                                           // [R][2048]
    __bf16* h_bf = (__bf16*)(Wb + 32768 + 16777216);             // 4 MB
    __bf16* c_bf = (__bf16*)(Wb + 32768 + 16777216 + 4194304);   // 2 MB
    __bf16* wts  = (__bf16*)(Wb + 32768 + 16777216 + 4194304 + 2097152);
    __bf16* a1_qt = wts;                      // contiguous q,k,v -> fused QKV Bt
    __bf16* a1_ot = wts + 3 * 262144;
    __bf16* a2_qt = wts + 4 * 262144;
    __bf16* a2_kt = wts + 5 * 262144;         // contiguous k,v -> fused KV Bt
    __bf16* a2_ot = wts + 7 * 262144;
    __bf16* ff1t  = wts + 8 * 262144;         // [4096][512]
    __bf16* ff2t  = ff1t + 2097152;           // [512][2048]

    dim3 blk(256);

    // ---- single merged prep dispatch -------------------------------------------
    PrepArgs pa;
    pa.t = t; pa.n1w = n1_w; pa.n1b = n1_b; pa.n2w = n2_w; pa.n2b = n2_b;
    pa.n4w = n4_w; pa.n4b = n4_b; pa.emb = emb;
    pa.ws[0] = a1_q; pa.ws[1] = a1_k; pa.ws[2] = a1_v; pa.ws[3] = a1_o;
    pa.ws[4] = a2_q; pa.ws[5] = a2_k; pa.ws[6] = a2_v; pa.ws[7] = a2_o;
    pa.wd[0] = a1_qt; pa.wd[1] = wts + 262144; pa.wd[2] = wts + 2 * 262144; pa.wd[3] = a1_ot;
    pa.wd[4] = a2_qt; pa.wd[5] = a2_kt; pa.wd[6] = wts + 6 * 262144; pa.wd[7] = a2_ot;
    pa.ffw1 = ff_w1; pa.ffw2 = ff_w2; pa.ff1t = ff1t; pa.ff2t = ff2t;
    pa.cond = cond; pa.cbf = c_bf; pa.B = B; pa.condN = Rc * D_MODEL;
    prep_kernel<<<dim3(1304 + (Rc * D_MODEL) / 1024), blk, 0, stream>>>(pa);

    // ---- block 1: self-attention -----------------------------------------------
    adaln_apply_kernel<<<dim3(R), blk, 0, stream>>>(x, emb, h_bf, N);
    gemm_bf16_kernel<2, 64><<<dim3(24, R / 128), blk, 0, stream>>>(
        h_bf, a1_qt, nullptr, nullptr, qkv, R, 512, 1536);
    attn_mfma_kernel<<<dim3(B * NHEADS * (N / 64)), blk, 0, stream>>>(
        qkv, qkv + 512, qkv + 1024, h_bf, N, N, 1536, 1536);
    gemm_bf16_kernel<1, 32><<<dim3(8, R / 64), blk, 0, stream>>>(
        h_bf, a1_ot, a1_ob, x, out, R, 512, 512);

    // ---- block 2: cross-attention ------------------------------------------------
    adaln_apply_kernel<<<dim3(R), blk, 0, stream>>>(
        out, emb + (size_t)B * 2 * D_MODEL, h_bf, N);
    gemm_dual_kernel<<<dim3(8 * (R / 64) + 16 * (Rc / 64)), blk, 0, stream>>>(
        h_bf, a2_qt, q2, R, c_bf, a2_kt, kv2, Rc);
    attn_mfma_kernel<<<dim3(B * NHEADS * (N / 64)), blk, 0, stream>>>(
        q2, kv2, kv2 + 512, h_bf, N, Nc, 512, 1024);
    gemm_bf16_kernel<1, 32><<<dim3(8, R / 64), blk, 0, stream>>>(
        h_bf, a2_ot, a2_ob, out, out, R, 512, 512);

    // ---- GEGLU feed-forward ---------------------------------------------------------
    adaln_apply_kernel<<<dim3(R), blk, 0, stream>>>(
        out, emb + (size_t)2 * B * 2 * D_MODEL, h_bf, N);
    gemm_geglu_bf16_kernel<<<dim3(32, R / 128), blk, 0, stream>>>(
        h_bf, ff1t, ff_b1, gg, R, 512);
    gemm_bf16_kernel<1, 32><<<dim3(8, R / 64), blk, 0, stream>>>(
        gg, ff2t, ff_b2, out, out, R, 2048, 512);
}